// Round 9
// baseline (12388.892 us; speedup 1.0000x reference)
//
#include <hip/hip_runtime.h>
#include <hip/hip_bf16.h>

// TTS: embed -> BiLSTM encoder -> K/V proj -> 1000-step autoregressive decode.
// v10 decode (two-batch interleave: hide the coherence RT under compute):
//  - v6/v7/v8/v9 all pin at ~5.7us/step regardless of syncs/VALU -> the step
//    is dominated by the agent-scope RT (Gbuf read ~900cy + drain ~900cy +
//    flag visibility/poll ~2us), compute only ~30%.
//  - v10: 128 blocks = (pair b0, slot sidx) x 512 thr; each block runs batch
//    b0 and b0+8 in alternating phases. Batch A's wait happens at the START
//    of A's next phase, with B's whole phase in between -> RT overlapped.
//    Weights are batch-independent: same 72 resident VGPRs serve both.
//    K/V/h state doubled in LDS (~145KB total, <=147KB proven in v7).
//  - Schedule shift: phase(s,t) = [t==2 partner guard] -> mel/stop(t-2)
//    (l_h still h_{t-2}) -> wait(flags>=t) -> P6 (h_{t-1}) -> P1 (step-t
//    partials, w2m aadd, rot reset) -> wave0 (q,QK,softmax,ctx) -> P5
//    (wcg aadd) -> arrive(t+1). Epilogue finishes mel/stop 998,999 + probs.
//  - Gbuf rot-3 safety under shifted wait: flag t from block X implies X
//    finished iter t-1, i.e. X already READ the step-(t-2) buffer; reset of
//    rot((t+1)%3) (== step t-2's) after wait(>=t) is race-free; next writer
//    waits flag t+1 which follows our reset via bar_arrive's drain.
// Sync: fence-free flag barriers; agent-scope RELAXED atomics. fp32 except
// bf16 Wcg/W2m. Numerics identical to v9 per batch.

typedef unsigned short u16;
typedef unsigned int   u32;
#define DI __device__ __forceinline__

// ---- ws layout (bytes) ----
static constexpr size_t WS_BAR   = 0;              // int flag lines: [0,32KB) decode, 64KB+ enc
static constexpr size_t WS_GBUF  = 64*1024;        // fp32 [3][16][768] 144KB (zeroed by k_init)
static constexpr size_t WS_HBUF  = 192*1024;       // legacy zero region
static constexpr size_t WS_PROBS = 208*1024;       // fp32 [16][8][128] 64KB
static constexpr size_t WS_BIAS  = 272*1024;       // fp32 bqp[512]|bg0[1024]|bgp[1024]
static constexpr size_t WS_W2M   = 320*1024;       // bf16 [1024][256] 512KB
static constexpr size_t WS_WQH   = 832*1024;       // fp32 [512][256]  512KB
static constexpr size_t WS_WCG   = 1344*1024;      // bf16 [1024][512] 1MB -> 2368KB

// ---- d_out scratch (float indices; d_out = 8,210,048 floats) ----
static constexpr size_t OF_ENC_A = 262144;         // fp32 [8][128][512] b=0..7
static constexpr size_t OF_ENC_B = 1286144;        // fp32 [8][128][512] b=8..15
static constexpr size_t OF_XWF   = 4015744;        // fp32 [2048][1024]
static constexpr size_t OF_XWB   = 6112896;        // fp32 [2048][1024] -> 8210048
// K/V slot (batch pair p=b>>1, sub s=b&1): outf + p*1024000 + s*131072 (K then V^T)

DI float bf2f(u16 u){ union{u32 i; float f;} v; v.i = ((u32)u)<<16; return v.f; }
DI u16 f2bf(float f){ union{float f; u32 i;} v; v.f = f;
  u32 r = v.i + 0x7fffu + ((v.i>>16)&1u); return (u16)(r>>16); }
DI float2 bf2x(u32 u){ union{u32 i; float f;} a,b; a.i = u<<16; b.i = u & 0xffff0000u;
  float2 r; r.x = a.f; r.y = b.f; return r; }
DI float dot8(uint4 wv, float4 a, float4 b){   // bf16 weights x fp32 acts
  float2 w0 = bf2x(wv.x), w1 = bf2x(wv.y), w2 = bf2x(wv.z), w3 = bf2x(wv.w);
  return w0.x*a.x + w0.y*a.y + w1.x*a.z + w1.y*a.w
       + w2.x*b.x + w2.y*b.y + w3.x*b.z + w3.y*b.w;
}
DI float dot8f(float4 wa, float4 wb, float4 a, float4 b){
  return wa.x*a.x + wa.y*a.y + wa.z*a.z + wa.w*a.w
       + wb.x*b.x + wb.y*b.y + wb.z*b.z + wb.w*b.w;
}
DI float sigm(float x){ return 1.f/(1.f + __expf(-x)); }

// agent-scope relaxed atomics: coherence-point access, no fence needed.
DI float afload(const float* p){
  return __hip_atomic_load(p, __ATOMIC_RELAXED, __HIP_MEMORY_SCOPE_AGENT);
}
DI void afstore(float* p, float v){
  __hip_atomic_store(p, v, __ATOMIC_RELAXED, __HIP_MEMORY_SCOPE_AGENT);
}
DI void aadd(float* p, float v){
  __hip_atomic_fetch_add(p, v, __ATOMIC_RELAXED, __HIP_MEMORY_SCOPE_AGENT);
}

// ---- fence-free flag barrier ----
DI void bar_arrive(int* flags, int myidx, int t){
  __syncthreads();
  if (threadIdx.x == 0){
    __builtin_amdgcn_s_waitcnt(0);
    __hip_atomic_store(flags + myidx*32, t, __ATOMIC_RELAXED, __HIP_MEMORY_SCOPE_AGENT);
  }
}
DI void bar_wait(int* flags, int n, int t){
  if (threadIdx.x < 64){
    const int idx = threadIdx.x & (n-1);
    int v = __hip_atomic_load(flags + idx*32, __ATOMIC_RELAXED, __HIP_MEMORY_SCOPE_AGENT);
    while (__any(v < t)){
      __builtin_amdgcn_s_sleep(1);
      if (v < t)
        v = __hip_atomic_load(flags + idx*32, __ATOMIC_RELAXED, __HIP_MEMORY_SCOPE_AGENT);
    }
  }
  __asm__ __volatile__("" ::: "memory");
  __syncthreads();
}

__global__ __launch_bounds__(256) void k_init(int* bars, float* hbuf){
  const int i = blockIdx.x*256 + threadIdx.x;   // 32 blocks
  for (int k = i; k < 49152; k += 32*256) bars[k] = 0;
  if (i < 4096) hbuf[i] = 0.f;
}

// fused embed + x@Wih.T + biases -> xw fp32. 2048 blocks.
__global__ __launch_bounds__(256) void k_xw(
    const int* __restrict__ tok, const int* __restrict__ spk,
    const float* __restrict__ et, const float* __restrict__ es,
    const float* __restrict__ WihF, const float* __restrict__ bihF, const float* __restrict__ bhhF,
    const float* __restrict__ WihB, const float* __restrict__ bihB, const float* __restrict__ bhhB,
    float* __restrict__ xwf, float* __restrict__ xwb){
  const int tid = threadIdx.x, bi = blockIdx.x;
  const int dir = bi & 1, jc = (bi >> 1) & 3, btg = bi >> 3;
  const int j = jc*256 + tid;
  const float* W = (dir ? WihB : WihF) + j*256;
  const float bias = (dir ? bihB : bihF)[j] + (dir ? bhhB : bhhF)[j];
  float* xw = dir ? xwb : xwf;

  __shared__ __align__(16) float lx[8][256];
  #pragma unroll
  for (int r = 0; r < 8; ++r){
    const int bt = btg*8 + r;
    lx[r][tid] = et[tok[bt]*256 + tid] + es[spk[bt>>7]*256 + tid];
  }
  __syncthreads();

  float acc[8];
  #pragma unroll
  for (int k2 = 0; k2 < 8; ++k2) acc[k2] = bias;
  for (int h = 0; h < 256; h += 8){
    float4 w0 = *(const float4*)(W + h);
    float4 w1 = *(const float4*)(W + h + 4);
    #pragma unroll
    for (int k2 = 0; k2 < 8; ++k2)
      acc[k2] += dot8f(w0, w1, *(const float4*)(&lx[k2][h]), *(const float4*)(&lx[k2][h+4]));
  }
  #pragma unroll
  for (int k2 = 0; k2 < 8; ++k2) xw[(btg*8 + k2)*1024 + j] = acc[k2];
}

// Wcg = W1@Wo -> bf16 [1024,512]; W2m = W2@Wmel -> bf16 [1024,256];
// Wqh = Wq@Wmel -> fp32 [512,256]. 896 blocks.
__global__ __launch_bounds__(256) void k_fuse(
    const float* __restrict__ decW, const float* __restrict__ Wo,
    const float* __restrict__ Wmel, const float* __restrict__ Wq,
    u16* __restrict__ Wcg, u16* __restrict__ W2m, float* __restrict__ Wqh){
  const int tid = threadIdx.x, blk = blockIdx.x;
  float acc[4] = {0.f,0.f,0.f,0.f};
  if (blk < 512){
    const int g0 = (blk >> 1)*4, e = (blk & 1)*256 + tid;
    for (int jj = 0; jj < 512; ++jj){
      float wo = Wo[jj*512 + e];
      #pragma unroll
      for (int i2 = 0; i2 < 4; ++i2) acc[i2] += decW[(g0+i2)*1024 + jj] * wo;
    }
    #pragma unroll
    for (int i2 = 0; i2 < 4; ++i2) Wcg[(g0+i2)*512 + e] = f2bf(acc[i2]);
  } else if (blk < 768){
    const int g0 = (blk - 512)*4, h = tid;
    for (int m = 0; m < 512; ++m){
      float wm = Wmel[m*256 + h];
      #pragma unroll
      for (int i2 = 0; i2 < 4; ++i2) acc[i2] += decW[(g0+i2)*1024 + 512 + m] * wm;
    }
    #pragma unroll
    for (int i2 = 0; i2 < 4; ++i2) W2m[(g0+i2)*256 + h] = f2bf(acc[i2]);
  } else {
    const int j0 = (blk - 768)*4, h = tid;
    for (int e = 0; e < 512; ++e){
      float wm = Wmel[e*256 + h];
      #pragma unroll
      for (int i2 = 0; i2 < 4; ++i2) acc[i2] += Wq[(j0+i2)*512 + e] * wm;
    }
    #pragma unroll
    for (int i2 = 0; i2 < 4; ++i2) Wqh[(j0+i2)*256 + h] = acc[i2];
  }
}

__global__ __launch_bounds__(256) void k_bias(
    const float* __restrict__ Wq, const float* __restrict__ bq, const float* __restrict__ bmel,
    const float* __restrict__ decW, const float* __restrict__ bo,
    const float* __restrict__ bih, const float* __restrict__ bhh, float* __restrict__ biasws){
  const int o = blockIdx.x*256 + threadIdx.x;   // 6 blocks -> 1536
  if (o < 512){
    float s = bq[o];
    for (int e = 0; e < 512; ++e) s += Wq[o*512 + e] * bmel[e];
    biasws[o] = s;                               // bq' = Wq@bmel + bq
  } else {
    const int gr = o - 512;
    float s1 = bih[gr] + bhh[gr];
    for (int jj = 0; jj < 512; ++jj) s1 += decW[gr*1024 + jj] * bo[jj];
    biasws[512 + gr] = s1;                       // bg0 = W1@bo + bih + bhh
    float s2 = s1;
    for (int m = 0; m < 512; ++m) s2 += decW[gr*1024 + 512 + m] * bmel[m];
    biasws[1536 + gr] = s2;                      // bg' = bg0 + W2@bmel
  }
}

// persistent BiLSTM encoder: 32 groups (dir,b) x 8 WGs x 128 thr. fp32.
__global__ __launch_bounds__(128) void k_enc(
    const float* __restrict__ xwf, const float* __restrict__ xwb,
    const float* __restrict__ WhhF, const float* __restrict__ WhhB,
    float* encA, float* encB, int* bars){
  const int tid = threadIdx.x;
  const int xcd = blockIdx.x & 7, sl = blockIdx.x >> 3;
  const int grp = xcd*4 + (sl >> 3);
  const int w = sl & 7;
  const int dir = grp & 1, b = grp >> 1;
  int* bar = bars + (16 + grp)*1024;
  const float* Whh = dir ? WhhB : WhhF;
  const float* xw = dir ? xwb : xwf;
  float* encb = (b < 8 ? encA : encB) + (size_t)(b & 7)*65536;
  const int q = tid >> 5, ii = tid & 31;
  const int j = q*256 + w*32 + ii;
  const float* wr = Whh + j*256;

  __shared__ __align__(16) float l_h[256];
  __shared__ float l_g[4][32];
  __shared__ float l_c[32];
  if (tid < 32) l_c[tid] = 0.f;
  __syncthreads();

  for (int it = 0; it < 128; ++it){
    const int ts = dir ? (127 - it) : it;
    float acc = xw[(b*128 + ts)*1024 + j];
    if (it > 0){
      const int tp = dir ? (ts + 1) : (ts - 1);
      const float* hp = encb + tp*512 + dir*256;
      for (int i = tid; i < 256; i += 128) l_h[i] = afload(hp + i);
      __syncthreads();
      #pragma unroll 4
      for (int k = 0; k < 256; k += 8)
        acc += dot8f(*(const float4*)(wr + k), *(const float4*)(wr + k + 4),
                     *(const float4*)(&l_h[k]), *(const float4*)(&l_h[k + 4]));
    }
    l_g[q][ii] = acc;
    __syncthreads();
    if (tid < 32){
      float ig = l_g[0][tid], fg = l_g[1][tid], gg = l_g[2][tid], og = l_g[3][tid];
      float c = sigm(fg)*l_c[tid] + sigm(ig)*tanhf(gg);
      l_c[tid] = c;
      afstore(encb + ts*512 + dir*256 + w*32 + tid, sigm(og)*tanhf(c));
    }
    bar_arrive(bar, w, it+1);
    bar_wait(bar, 8, it+1);
  }
}

// K,V projections fp32 -> per-pair slot in d_out. 1024 blocks.
__global__ __launch_bounds__(256) void k_proj(
    const float* __restrict__ encA, const float* __restrict__ encB,
    const float* __restrict__ Wk, const float* __restrict__ bk,
    const float* __restrict__ Wv, const float* __restrict__ bv,
    float* outf){
  const int tid = threadIdx.x, x = blockIdx.x;
  const int role = x & 1, dc = (x >> 1) & 1, btg = x >> 2;
  const int row = dc*256 + tid;
  const float* W = (role ? Wv : Wk) + row*512;
  const float bias = (role ? bv : bk)[row];
  const int b = (btg*8) >> 7;
  const float* eb = (b < 8 ? encA : encB) + (size_t)(b & 7)*65536;
  float acc[8];
  #pragma unroll
  for (int k2 = 0; k2 < 8; ++k2) acc[k2] = bias;
  for (int e = 0; e < 512; e += 8){
    float4 wa = *(const float4*)(W + e);
    float4 wb = *(const float4*)(W + e + 4);
    #pragma unroll
    for (int k2 = 0; k2 < 8; ++k2){
      const float* ep = eb + ((btg*8 + k2) & 127)*512 + e;
      acc[k2] += dot8f(wa, wb, *(const float4*)(ep), *(const float4*)(ep + 4));
    }
  }
  const int head = row >> 6, dd = row & 63;
  float* kv = outf + (size_t)(b >> 1)*1024000 + (size_t)(b & 1)*131072;
  #pragma unroll
  for (int k2 = 0; k2 < 8; ++k2){
    const int ts = (btg*8 + k2) & 127;
    if (role == 0) kv[head*8192 + ts*64 + dd] = acc[k2];
    else           kv[65536 + head*8192 + dd*128 + ts] = acc[k2];
  }
}

// persistent decoder v10: 128 blocks = (pair b0, slot sidx) x 512 thr; two
// batches (b0, b0+8) interleaved per block so each batch's coherence RT is
// hidden under the other batch's compute phase.
__global__ __launch_bounds__(512) void k_decode(
    const float* __restrict__ Wqh,   // [512][256] fp32
    const u16*   __restrict__ Wcg,   // [1024][512] bf16
    const u16*   __restrict__ W2m,   // [1024][256] bf16
    const float* __restrict__ Wmel,  // [512][256] fp32 (streamed per phase)
    const float* __restrict__ bmel,
    const float* __restrict__ Wstop, const float* __restrict__ bstop,
    const float* __restrict__ bq,    // original bq [512]
    const float* __restrict__ biasws,// bqp[512] | bg0[1024] | bgp[1024]
    float* Gbuf,                     // [3][16][768] gate accumulators (zeroed)
    float* probs, int* bars,
    float* out){                     // K/V slots alias mel region (prelude-only reads)
  const int tid = threadIdx.x;
  const int b0 = blockIdx.x & 7, sidx = blockIdx.x >> 3;   // pair, slot
  const int h = sidx >> 1, half = sidx & 1;                // head, row-half
  const int d = tid & 63, ko = tid >> 6;                   // 64 dims x 8 k-chunks
  float* out_mel  = out;
  float* out_stop = out + 8192000;
  float* out_attn = out + 8208000;

  // Doubled per-batch state; strides 68/132/36 are 2-way/free for b128
  // (16-lane phase bank model, verified v6/v8/v9 counters).
  __shared__ __align__(16) float lK[2][128*68];
  __shared__ __align__(16) float lV[2][64*132];
  __shared__ __align__(16) float l_h[2][256];
  __shared__ __align__(16) float l_hw[2][288];  // staggered replica: chunk c at +c*36
  __shared__ __align__(16) float l_q[64];
  __shared__ __align__(16) float l_p[2][128];   // UNNORMALIZED exp(s-M), per batch
  __shared__ __align__(16) float l_ct[64];      // normalized ctx (transient)
  __shared__ __align__(16) float l_qt[8][64];   // q partials (transient)
  __shared__ float l_r[2];                      // S per batch (epilogue probs)

  const int rg = tid >> 2, c4 = tid & 3;        // Wcg roles: rows rg*3..+2, cols c4*16..+16
  const int rw = tid >> 3, c8 = tid & 7;        // w2m roles
  const int r2 = half*384 + h*48 + rw;          // w2m packed row

  // ---- prelude: K,V of head h for BOTH batches -> LDS ----
  #pragma unroll
  for (int s = 0; s < 2; ++s){
    const int bb = b0 + 8*s;
    const float* kvs = out + (size_t)(bb >> 1)*1024000 + (size_t)(bb & 1)*131072;
    const float* gK = kvs + h*8192;
    for (int i = tid; i < 2048; i += 512){
      const int r = i >> 4, c = i & 15;
      *(float4*)(&lK[s][r*68 + c*4]) = *(const float4*)(gK + r*64 + c*4);
    }
    const float* gV = kvs + 65536 + h*8192;
    for (int i = tid; i < 2048; i += 512){
      const int r = i >> 5, c = i & 31;
      *(float4*)(&lV[s][r*132 + c*4]) = *(const float4*)(gV + r*128 + c*4);
    }
  }

  // ---- persistent weights -> VGPRs (72/thread; batch-independent) ----
  float4 wq[8];   // Wqh row h*64+d, cols ko*32..+32  (32 VGPR)
  {
    const float* p = Wqh + (h*64 + d)*256 + ko*32;
    #pragma unroll
    for (int j = 0; j < 8; ++j) wq[j] = *(const float4*)(p + 4*j);
  }
  uint4 wcg[3][2];   // Wcg rows rg*3..+2 of this half's {i,g,o}, cols c4*16..+16
  #pragma unroll
  for (int s = 0; s < 3; ++s){
    const int r = half*384 + rg*3 + s;           // packed row 0..767
    const int orig = r + (r >= 256 ? 256 : 0);   // skip dead f-rows
    const u16* p = Wcg + orig*512 + h*64 + c4*16;
    wcg[s][0] = *(const uint4*)(p);
    wcg[s][1] = *(const uint4*)(p + 8);
  }
  uint4 w2[4];    // W2m packed row r2, cols c8*32..+32 (tid<384; 16 VGPR)
  {
    const int orig2 = r2 + (r2 >= 256 ? 256 : 0);
    const u16* p = W2m + (tid < 384 ? orig2*256 + c8*32 : 0);
    #pragma unroll
    for (int j = 0; j < 4; ++j) w2[j] = *(const uint4*)(p + 8*j);
  }
  // biases (batch-independent)
  const float bq0 = bq[h*64 + d];
  const float bq1 = biasws[h*64 + d];
  const float bmd = bmel[h*64 + half*32 + ((tid & 255) >> 3)];
  float bgi0=0, bgg0=0, bgo0=0, bgi1=0, bgg1=0, bgo1=0;
  if (tid < 256){
    bgi0 = biasws[ 512 + tid]; bgg0 = biasws[1024 + tid]; bgo0 = biasws[1280 + tid];
    bgi1 = biasws[1536 + tid]; bgg1 = biasws[2048 + tid]; bgo1 = biasws[2304 + tid];
  }
  float4 wst4 = {0.f,0.f,0.f,0.f};
  if (h == 0 && half == 1 && tid < 64) wst4 = *(const float4*)(Wstop + tid*4);
  const float bst = bstop[0];

  if (tid < 256){ l_h[0][tid] = 0.f; l_h[1][tid] = 0.f; }
  if (tid < 288){ l_hw[0][tid] = 0.f; l_hw[1][tid] = 0.f; }
  __syncthreads();

  for (int t = 0; t < 1000; ++t){
    #pragma unroll
    for (int s = 0; s < 2; ++s){
      const int bb = b0 + 8*s;
      int* bflag = bars + bb*512;
      float* lHs  = l_h[s];
      float* lHws = l_hw[s];
      const float* lKs = lK[s];
      const float* lVs = lV[s];
      float* lPs = l_p[s];
      // ---- deferred mel/stop for step t-2 (lHs/lHws still h_{t-2}) ----
      if (t == 2) bar_wait(bars + (bb ^ 1)*512, 16, 1);  // partner preludes done
      if (t >= 2){
        if (tid < 256){
          const int dd = half*32 + (tid >> 3), cc = tid & 7;
          const float* pm = Wmel + (h*64 + dd)*256 + cc*32;
          const float4* hh = (const float4*)(lHws + cc*36);
          float mp = dot8f(*(const float4*)(pm),      *(const float4*)(pm + 4),  hh[0], hh[1])
                   + dot8f(*(const float4*)(pm + 8),  *(const float4*)(pm + 12), hh[2], hh[3])
                   + dot8f(*(const float4*)(pm + 16), *(const float4*)(pm + 20), hh[4], hh[5])
                   + dot8f(*(const float4*)(pm + 24), *(const float4*)(pm + 28), hh[6], hh[7]);
          mp += __shfl_xor(mp, 1); mp += __shfl_xor(mp, 2); mp += __shfl_xor(mp, 4);
          if (cc == 0) out_mel[((size_t)bb*1000 + (t-2))*512 + h*64 + dd] = mp + bmd;
        }
        if (h == 0 && half == 1 && tid < 64){
          const float4 h4v = *(const float4*)(lHs + tid*4);
          float sp = wst4.x*h4v.x + wst4.y*h4v.y + wst4.z*h4v.z + wst4.w*h4v.w;
          #pragma unroll
          for (int off = 32; off; off >>= 1) sp += __shfl_xor(sp, off);
          if (tid == 0) out_stop[bb*1000 + (t-2)] = sp + bst;
        }
      }
      // ---- wait for step-(t-1) reduction (RT hidden by other batch) + P6 ----
      if (t >= 1){
        bar_wait(bflag, 16, t);
        const float* bufP = Gbuf + (((t-1)%3)*16 + bb)*768;
        if (tid < 256){
          float gi = (t == 1 ? bgi0 : bgi1) + afload(bufP + tid);
          float gg = (t == 1 ? bgg0 : bgg1) + afload(bufP + 256 + tid);
          float go = (t == 1 ? bgo0 : bgo1) + afload(bufP + 512 + tid);
          float c = sigm(gi) * tanhf(gg);        // decoder c_prev == 0 every step
          float hv = sigm(go) * tanhf(c);
          lHs[tid] = hv;
          lHws[(tid >> 5)*36 + (tid & 31)] = hv;
        }
        __syncthreads();
      }
      float* buf = Gbuf + ((t%3)*16 + bb)*768;
      // ---- P1: q partials + W2m partials -> aadd + rot reset ----
      {
        const float4* hh = (const float4*)(lHs + ko*32);
        l_qt[ko][d] = dot8f(wq[0], wq[1], hh[0], hh[1]) + dot8f(wq[2], wq[3], hh[2], hh[3])
                    + dot8f(wq[4], wq[5], hh[4], hh[5]) + dot8f(wq[6], wq[7], hh[6], hh[7]);
      }
      if (tid < 384){
        const float4* hh = (const float4*)(lHws + c8*36);
        float w2p = dot8(w2[0], hh[0], hh[1]) + dot8(w2[1], hh[2], hh[3])
                  + dot8(w2[2], hh[4], hh[5]) + dot8(w2[3], hh[6], hh[7]);
        w2p += __shfl_xor(w2p, 1);
        w2p += __shfl_xor(w2p, 2);
        w2p += __shfl_xor(w2p, 4);               // combine 8 col-chunks
        if (c8 == 0) aadd(buf + r2, w2p);
      } else if (t >= 2 && tid >= 432 && tid < 480){
        // reset step-(t-2)'s buffer (== step t+1's): all peers read it at
        // iter t-1 (flag t implies so); our arrive(t+1) drains this store
        // before any peer's step-(t+1) writes (they wait flag t+1).
        const int rr = (t+1)%3;
        afstore(Gbuf + (rr*16 + bb)*768 + sidx*48 + (tid - 432), 0.f);
      }
      __syncthreads();
      // ---- wave0: q assemble, QK^T, softmax, ctx (no internal barriers) ----
      if (tid < 64){
        float qq = (t == 0 ? bq0 : bq1);
        #pragma unroll
        for (int k = 0; k < 8; ++k) qq += l_qt[k][tid];
        l_q[tid] = qq;
        __asm__ __volatile__("s_waitcnt lgkmcnt(0)" ::: "memory");
        const float* kr0 = lKs + tid*68;
        const float* kr1 = lKs + (tid + 64)*68;
        float s0 = 0.f, s1 = 0.f;
        #pragma unroll
        for (int k = 0; k < 64; k += 8){
          float4 qa = *(const float4*)(l_q + k), qb = *(const float4*)(l_q + k + 4);
          s0 += dot8f(*(const float4*)(kr0 + k), *(const float4*)(kr0 + k + 4), qa, qb);
          s1 += dot8f(*(const float4*)(kr1 + k), *(const float4*)(kr1 + k + 4), qa, qb);
        }
        s0 *= 0.125f; s1 *= 0.125f;
        float m = fmaxf(s0, s1);
        #pragma unroll
        for (int off = 32; off; off >>= 1) m = fmaxf(m, __shfl_xor(m, off));
        float p0 = __expf(s0 - m), p1 = __expf(s1 - m);
        float ss = p0 + p1;
        #pragma unroll
        for (int off = 32; off; off >>= 1) ss += __shfl_xor(ss, off);
        lPs[tid] = p0; lPs[tid + 64] = p1;
        __asm__ __volatile__("s_waitcnt lgkmcnt(0)" ::: "memory");
        const float* vr = lVs + tid*132;         // row-per-lane, 2-way free
        float cs = 0.f;
        #pragma unroll
        for (int k = 0; k < 128; k += 8)
          cs += dot8f(*(const float4*)(vr + k), *(const float4*)(vr + k + 4),
                      *(const float4*)(lPs + k), *(const float4*)(lPs + k + 4));
        l_ct[tid] = cs / ss;
        if (tid == 0) l_r[s] = ss;
      }
      __syncthreads();
      // ---- P5: Wcg gate partials (registers) -> per-batch aadd ----
      {
        const float4* ct = (const float4*)(l_ct + c4*16);
        float4 c0 = ct[0], c1 = ct[1], c2 = ct[2], c3 = ct[3];
        float pr0 = dot8(wcg[0][0], c0, c1) + dot8(wcg[0][1], c2, c3);
        float pr1 = dot8(wcg[1][0], c0, c1) + dot8(wcg[1][1], c2, c3);
        float pr2 = dot8(wcg[2][0], c0, c1) + dot8(wcg[2][1], c2, c3);
        pr0 += __shfl_xor(pr0, 1); pr0 += __shfl_xor(pr0, 2);
        pr1 += __shfl_xor(pr1, 1); pr1 += __shfl_xor(pr1, 2);
        pr2 += __shfl_xor(pr2, 1); pr2 += __shfl_xor(pr2, 2);
        if (c4 == 0){
          const int rb = half*384 + rg*3;
          aadd(buf + rb,     pr0);
          aadd(buf + rb + 1, pr1);
          aadd(buf + rb + 2, pr2);
        }
      }
      bar_arrive(bflag, sidx, t+1);              // drains adds + reset, then flag
    }
  }

  // ---- epilogue per batch: mel/stop 998 & 999, probs; then attn ----
  #pragma unroll
  for (int s = 0; s < 2; ++s){
    const int bb = b0 + 8*s;
    int* bflag = bars + bb*512;
    float* lHs  = l_h[s];
    float* lHws = l_hw[s];
    float* lPs  = l_p[s];
    #pragma unroll
    for (int e = 0; e < 2; ++e){
      const int tm = 998 + e;                    // emit mel/stop(tm) from h_tm
      if (e == 1){
        bar_wait(bflag, 16, 1000);
        const float* bufP = Gbuf + ((999%3)*16 + bb)*768;
        if (tid < 256){
          float gi = bgi1 + afload(bufP + tid);
          float gg = bgg1 + afload(bufP + 256 + tid);
          float go = bgo1 + afload(bufP + 512 + tid);
          float c = sigm(gi) * tanhf(gg);
          float hv = sigm(go) * tanhf(c);
          lHs[tid] = hv;
          lHws[(tid >> 5)*36 + (tid & 31)] = hv;
        }
        __syncthreads();
      }
      if (tid < 256){
        const int dd = half*32 + (tid >> 3), cc = tid & 7;
        const float* pm = Wmel + (h*64 + dd)*256 + cc*32;
        const float4* hh = (const float4*)(lHws + cc*36);
        float mp = dot8f(*(const float4*)(pm),      *(const float4*)(pm + 4),  hh[0], hh[1])
                 + dot8f(*(const float4*)(pm + 8),  *(const float4*)(pm + 12), hh[2], hh[3])
                 + dot8f(*(const float4*)(pm + 16), *(const float4*)(pm + 20), hh[4], hh[5])
                 + dot8f(*(const float4*)(pm + 24), *(const float4*)(pm + 28), hh[6], hh[7]);
        mp += __shfl_xor(mp, 1); mp += __shfl_xor(mp, 2); mp += __shfl_xor(mp, 4);
        if (cc == 0) out_mel[((size_t)bb*1000 + tm)*512 + h*64 + dd] = mp + bmd;
      }
      if (h == 0 && half == 1 && tid < 64){
        const float4 h4v = *(const float4*)(lHs + tid*4);
        float sp = wst4.x*h4v.x + wst4.y*h4v.y + wst4.z*h4v.z + wst4.w*h4v.w;
        #pragma unroll
        for (int off = 32; off; off >>= 1) sp += __shfl_xor(sp, off);
        if (tid == 0) out_stop[bb*1000 + tm] = sp + bst;
      }
    }
    if (half == 0 && tid < 128)   // lPs/l_r hold step-999 values; normalize
      afstore(probs + (bb*8 + h)*128 + tid, lPs[tid] / l_r[s]);
    bar_arrive(bflag, sidx, 1001);               // probs drained before flag
  }
  #pragma unroll
  for (int s = 0; s < 2; ++s){
    const int bb = b0 + 8*s;
    if (h == 0 && half == 0){
      bar_wait(bars + bb*512, 16, 1001);
      if (tid < 128){
        float ssum = 0.f;
        #pragma unroll
        for (int hh = 0; hh < 8; ++hh) ssum += afload(probs + (bb*8 + hh)*128 + tid);
        out_attn[bb*128 + tid] = ssum * 0.125f;
      }
    }
  }
}

extern "C" void kernel_launch(void* const* d_in, const int* in_sizes, int n_in,
                              void* d_out, int out_size, void* d_ws, size_t ws_size,
                              hipStream_t stream){
  const int*   tok = (const int*)d_in[0];
  const int*   spk = (const int*)d_in[1];
  const float* emb_text = (const float*)d_in[2];
  const float* emb_spk  = (const float*)d_in[3];
  const float* WihF = (const float*)d_in[4];
  const float* WhhF = (const float*)d_in[5];
  const float* bihF = (const float*)d_in[6];
  const float* bhhF = (const float*)d_in[7];
  const float* WihB = (const float*)d_in[8];
  const float* WhhB = (const float*)d_in[9];
  const float* bihB = (const float*)d_in[10];
  const float* bhhB = (const float*)d_in[11];
  const float* Wq = (const float*)d_in[12];
  const float* bq = (const float*)d_in[13];
  const float* Wk = (const float*)d_in[14];
  const float* bk = (const float*)d_in[15];
  const float* Wv = (const float*)d_in[16];
  const float* bv = (const float*)d_in[17];
  const float* Wo = (const float*)d_in[18];
  const float* bo = (const float*)d_in[19];
  const float* decW = (const float*)d_in[20];
  /* d_in[21] dec_Whh dead (state re-zeroed every step) */
  const float* bih = (const float*)d_in[22];
  const float* bhh = (const float*)d_in[23];
  const float* Wmel = (const float*)d_in[24];
  const float* bmel = (const float*)d_in[25];
  const float* Wstop = (const float*)d_in[26];
  const float* bstop = (const float*)d_in[27];

  char* ws = (char*)d_ws;
  int*   bars   = (int*)(ws + WS_BAR);
  float* Gbuf   = (float*)(ws + WS_GBUF);
  float* hbuf   = (float*)(ws + WS_HBUF);
  float* probs  = (float*)(ws + WS_PROBS);
  float* biasws = (float*)(ws + WS_BIAS);
  u16*   W2m    = (u16*)(ws + WS_W2M);
  float* Wqh    = (float*)(ws + WS_WQH);
  u16*   Wcg    = (u16*)(ws + WS_WCG);

  float* outf = (float*)d_out;
  float* encA = outf + OF_ENC_A;
  float* encB = outf + OF_ENC_B;
  float* xwf  = outf + OF_XWF;
  float* xwb  = outf + OF_XWB;

  k_init <<<32,   256, 0, stream>>>(bars, hbuf);
  k_xw   <<<2048, 256, 0, stream>>>(tok, spk, emb_text, emb_spk,
                                    WihF, bihF, bhhF, WihB, bihB, bhhB, xwf, xwb);
  k_enc  <<<256,  128, 0, stream>>>(xwf, xwb, WhhF, WhhB, encA, encB, bars);
  k_fuse <<<896,  256, 0, stream>>>(decW, Wo, Wmel, Wq, Wcg, W2m, Wqh);
  k_bias <<<6,    256, 0, stream>>>(Wq, bq, bmel, decW, bo, bih, bhh, biasws);
  k_proj <<<1024, 256, 0, stream>>>(encA, encB, Wk, bk, Wv, bv, outf);
  k_decode<<<128, 512, 0, stream>>>(Wqh, Wcg, W2m, Wmel, bmel, Wstop, bstop,
                                    bq, biasws, Gbuf, probs, bars, outf);
}

// Round 10
// 8539.519 us; speedup vs baseline: 1.4508x; 1.4508x over previous
//
#include <hip/hip_runtime.h>
#include <hip/hip_bf16.h>

// TTS: embed -> BiLSTM encoder -> K/V proj -> 1000-step autoregressive decode.
// v11 decode (fuse both batches into ONE serial chain per iteration):
//  - v10 falsified "flag-prop dominates": a whole phase of slack changed
//    nothing (5.63us/batch-step == v9's 5.70). The step is serial-internal:
//    poll RT (~0.9) + Gbuf read RT (~0.9) + aadd drain (~0.9) + compute (~2)
//    + barriers (~0.5). v10 paid that chain twice per iteration.
//  - v11: the same 16 blocks handle batches b0 and b0+8 -> fuse:
//    * ONE flag set per (b0,slot) covers both batches (1 poll RT/iter).
//    * Gbuf loads for both batches issued together, covered by both
//      batches' mel/stop(t-2) work.
//    * one consume, one P1 (dots x2), softmax/ctx on TWO PARALLEL WAVES
//      (tid<64 batch A, tid 64..127 batch B), one P5 (dots x2), ONE
//      arrive whose drain covers both batches' atomics.
//    Serial RTs/iter: poll + drain (~1.8us) for TWO batch-steps.
//  - iter t: wait(t) -> issue Gbuf(t-1) -> mel/stop(t-2) -> sync ->
//    consume h_{t-1} -> sync -> P1(step t)+w2m aadds+rot reset -> sync ->
//    wave0 x2 -> sync -> P5 wcg aadds -> arrive(t+1).
//    Epilogue: mel/stop 998,999 + probs + head-avg attn.
//  - Gbuf rot-3 unchanged per real batch; reset lanes 384..479 (48/batch).
//    t==2 partner guard (b0^1 flags >=1) before first mel (K/V alias).
// Sync: fence-free flag barriers; agent-scope RELAXED atomics. fp32 except
// bf16 Wcg/W2m. Numerics identical to v9/v10 per batch.

typedef unsigned short u16;
typedef unsigned int   u32;
#define DI __device__ __forceinline__

// ---- ws layout (bytes) ----
static constexpr size_t WS_BAR   = 0;              // int flag lines: [0,32KB) decode, 64KB+ enc
static constexpr size_t WS_GBUF  = 64*1024;        // fp32 [3][16][768] 144KB (zeroed by k_init)
static constexpr size_t WS_HBUF  = 192*1024;       // legacy zero region
static constexpr size_t WS_PROBS = 208*1024;       // fp32 [16][8][128] 64KB
static constexpr size_t WS_BIAS  = 272*1024;       // fp32 bqp[512]|bg0[1024]|bgp[1024]
static constexpr size_t WS_W2M   = 320*1024;       // bf16 [1024][256] 512KB
static constexpr size_t WS_WQH   = 832*1024;       // fp32 [512][256]  512KB
static constexpr size_t WS_WCG   = 1344*1024;      // bf16 [1024][512] 1MB -> 2368KB

// ---- d_out scratch (float indices; d_out = 8,210,048 floats) ----
static constexpr size_t OF_ENC_A = 262144;         // fp32 [8][128][512] b=0..7
static constexpr size_t OF_ENC_B = 1286144;        // fp32 [8][128][512] b=8..15
static constexpr size_t OF_XWF   = 4015744;        // fp32 [2048][1024]
static constexpr size_t OF_XWB   = 6112896;        // fp32 [2048][1024] -> 8210048
// K/V slot (batch pair p=b>>1, sub s=b&1): outf + p*1024000 + s*131072 (K then V^T)

DI float bf2f(u16 u){ union{u32 i; float f;} v; v.i = ((u32)u)<<16; return v.f; }
DI u16 f2bf(float f){ union{float f; u32 i;} v; v.f = f;
  u32 r = v.i + 0x7fffu + ((v.i>>16)&1u); return (u16)(r>>16); }
DI float2 bf2x(u32 u){ union{u32 i; float f;} a,b; a.i = u<<16; b.i = u & 0xffff0000u;
  float2 r; r.x = a.f; r.y = b.f; return r; }
DI float dot8(uint4 wv, float4 a, float4 b){   // bf16 weights x fp32 acts
  float2 w0 = bf2x(wv.x), w1 = bf2x(wv.y), w2 = bf2x(wv.z), w3 = bf2x(wv.w);
  return w0.x*a.x + w0.y*a.y + w1.x*a.z + w1.y*a.w
       + w2.x*b.x + w2.y*b.y + w3.x*b.z + w3.y*b.w;
}
DI float dot8f(float4 wa, float4 wb, float4 a, float4 b){
  return wa.x*a.x + wa.y*a.y + wa.z*a.z + wa.w*a.w
       + wb.x*b.x + wb.y*b.y + wb.z*b.z + wb.w*b.w;
}
DI float sigm(float x){ return 1.f/(1.f + __expf(-x)); }

// agent-scope relaxed atomics: coherence-point access, no fence needed.
DI float afload(const float* p){
  return __hip_atomic_load(p, __ATOMIC_RELAXED, __HIP_MEMORY_SCOPE_AGENT);
}
DI void afstore(float* p, float v){
  __hip_atomic_store(p, v, __ATOMIC_RELAXED, __HIP_MEMORY_SCOPE_AGENT);
}
DI void aadd(float* p, float v){
  __hip_atomic_fetch_add(p, v, __ATOMIC_RELAXED, __HIP_MEMORY_SCOPE_AGENT);
}

// ---- fence-free flag barrier ----
DI void bar_arrive(int* flags, int myidx, int t){
  __syncthreads();   // each wave drains vmem at barrier (compiler vmcnt(0))
  if (threadIdx.x == 0){
    __builtin_amdgcn_s_waitcnt(0);
    __hip_atomic_store(flags + myidx*32, t, __ATOMIC_RELAXED, __HIP_MEMORY_SCOPE_AGENT);
  }
}
DI void bar_wait(int* flags, int n, int t){
  if (threadIdx.x < 64){
    const int idx = threadIdx.x & (n-1);
    int v = __hip_atomic_load(flags + idx*32, __ATOMIC_RELAXED, __HIP_MEMORY_SCOPE_AGENT);
    while (__any(v < t)){
      __builtin_amdgcn_s_sleep(1);
      if (v < t)
        v = __hip_atomic_load(flags + idx*32, __ATOMIC_RELAXED, __HIP_MEMORY_SCOPE_AGENT);
    }
  }
  __asm__ __volatile__("" ::: "memory");
  __syncthreads();
}

__global__ __launch_bounds__(256) void k_init(int* bars, float* hbuf){
  const int i = blockIdx.x*256 + threadIdx.x;   // 32 blocks
  for (int k = i; k < 49152; k += 32*256) bars[k] = 0;
  if (i < 4096) hbuf[i] = 0.f;
}

// fused embed + x@Wih.T + biases -> xw fp32. 2048 blocks.
__global__ __launch_bounds__(256) void k_xw(
    const int* __restrict__ tok, const int* __restrict__ spk,
    const float* __restrict__ et, const float* __restrict__ es,
    const float* __restrict__ WihF, const float* __restrict__ bihF, const float* __restrict__ bhhF,
    const float* __restrict__ WihB, const float* __restrict__ bihB, const float* __restrict__ bhhB,
    float* __restrict__ xwf, float* __restrict__ xwb){
  const int tid = threadIdx.x, bi = blockIdx.x;
  const int dir = bi & 1, jc = (bi >> 1) & 3, btg = bi >> 3;
  const int j = jc*256 + tid;
  const float* W = (dir ? WihB : WihF) + j*256;
  const float bias = (dir ? bihB : bihF)[j] + (dir ? bhhB : bhhF)[j];
  float* xw = dir ? xwb : xwf;

  __shared__ __align__(16) float lx[8][256];
  #pragma unroll
  for (int r = 0; r < 8; ++r){
    const int bt = btg*8 + r;
    lx[r][tid] = et[tok[bt]*256 + tid] + es[spk[bt>>7]*256 + tid];
  }
  __syncthreads();

  float acc[8];
  #pragma unroll
  for (int k2 = 0; k2 < 8; ++k2) acc[k2] = bias;
  for (int h = 0; h < 256; h += 8){
    float4 w0 = *(const float4*)(W + h);
    float4 w1 = *(const float4*)(W + h + 4);
    #pragma unroll
    for (int k2 = 0; k2 < 8; ++k2)
      acc[k2] += dot8f(w0, w1, *(const float4*)(&lx[k2][h]), *(const float4*)(&lx[k2][h+4]));
  }
  #pragma unroll
  for (int k2 = 0; k2 < 8; ++k2) xw[(btg*8 + k2)*1024 + j] = acc[k2];
}

// Wcg = W1@Wo -> bf16 [1024,512]; W2m = W2@Wmel -> bf16 [1024,256];
// Wqh = Wq@Wmel -> fp32 [512,256]. 896 blocks.
__global__ __launch_bounds__(256) void k_fuse(
    const float* __restrict__ decW, const float* __restrict__ Wo,
    const float* __restrict__ Wmel, const float* __restrict__ Wq,
    u16* __restrict__ Wcg, u16* __restrict__ W2m, float* __restrict__ Wqh){
  const int tid = threadIdx.x, blk = blockIdx.x;
  float acc[4] = {0.f,0.f,0.f,0.f};
  if (blk < 512){
    const int g0 = (blk >> 1)*4, e = (blk & 1)*256 + tid;
    for (int jj = 0; jj < 512; ++jj){
      float wo = Wo[jj*512 + e];
      #pragma unroll
      for (int i2 = 0; i2 < 4; ++i2) acc[i2] += decW[(g0+i2)*1024 + jj] * wo;
    }
    #pragma unroll
    for (int i2 = 0; i2 < 4; ++i2) Wcg[(g0+i2)*512 + e] = f2bf(acc[i2]);
  } else if (blk < 768){
    const int g0 = (blk - 512)*4, h = tid;
    for (int m = 0; m < 512; ++m){
      float wm = Wmel[m*256 + h];
      #pragma unroll
      for (int i2 = 0; i2 < 4; ++i2) acc[i2] += decW[(g0+i2)*1024 + 512 + m] * wm;
    }
    #pragma unroll
    for (int i2 = 0; i2 < 4; ++i2) W2m[(g0+i2)*256 + h] = f2bf(acc[i2]);
  } else {
    const int j0 = (blk - 768)*4, h = tid;
    for (int e = 0; e < 512; ++e){
      float wm = Wmel[e*256 + h];
      #pragma unroll
      for (int i2 = 0; i2 < 4; ++i2) acc[i2] += Wq[(j0+i2)*512 + e] * wm;
    }
    #pragma unroll
    for (int i2 = 0; i2 < 4; ++i2) Wqh[(j0+i2)*256 + h] = acc[i2];
  }
}

__global__ __launch_bounds__(256) void k_bias(
    const float* __restrict__ Wq, const float* __restrict__ bq, const float* __restrict__ bmel,
    const float* __restrict__ decW, const float* __restrict__ bo,
    const float* __restrict__ bih, const float* __restrict__ bhh, float* __restrict__ biasws){
  const int o = blockIdx.x*256 + threadIdx.x;   // 6 blocks -> 1536
  if (o < 512){
    float s = bq[o];
    for (int e = 0; e < 512; ++e) s += Wq[o*512 + e] * bmel[e];
    biasws[o] = s;                               // bq' = Wq@bmel + bq
  } else {
    const int gr = o - 512;
    float s1 = bih[gr] + bhh[gr];
    for (int jj = 0; jj < 512; ++jj) s1 += decW[gr*1024 + jj] * bo[jj];
    biasws[512 + gr] = s1;                       // bg0 = W1@bo + bih + bhh
    float s2 = s1;
    for (int m = 0; m < 512; ++m) s2 += decW[gr*1024 + 512 + m] * bmel[m];
    biasws[1536 + gr] = s2;                      // bg' = bg0 + W2@bmel
  }
}

// persistent BiLSTM encoder: 32 groups (dir,b) x 8 WGs x 128 thr. fp32.
__global__ __launch_bounds__(128) void k_enc(
    const float* __restrict__ xwf, const float* __restrict__ xwb,
    const float* __restrict__ WhhF, const float* __restrict__ WhhB,
    float* encA, float* encB, int* bars){
  const int tid = threadIdx.x;
  const int xcd = blockIdx.x & 7, sl = blockIdx.x >> 3;
  const int grp = xcd*4 + (sl >> 3);
  const int w = sl & 7;
  const int dir = grp & 1, b = grp >> 1;
  int* bar = bars + (16 + grp)*1024;
  const float* Whh = dir ? WhhB : WhhF;
  const float* xw = dir ? xwb : xwf;
  float* encb = (b < 8 ? encA : encB) + (size_t)(b & 7)*65536;
  const int q = tid >> 5, ii = tid & 31;
  const int j = q*256 + w*32 + ii;
  const float* wr = Whh + j*256;

  __shared__ __align__(16) float l_h[256];
  __shared__ float l_g[4][32];
  __shared__ float l_c[32];
  if (tid < 32) l_c[tid] = 0.f;
  __syncthreads();

  for (int it = 0; it < 128; ++it){
    const int ts = dir ? (127 - it) : it;
    float acc = xw[(b*128 + ts)*1024 + j];
    if (it > 0){
      const int tp = dir ? (ts + 1) : (ts - 1);
      const float* hp = encb + tp*512 + dir*256;
      for (int i = tid; i < 256; i += 128) l_h[i] = afload(hp + i);
      __syncthreads();
      #pragma unroll 4
      for (int k = 0; k < 256; k += 8)
        acc += dot8f(*(const float4*)(wr + k), *(const float4*)(wr + k + 4),
                     *(const float4*)(&l_h[k]), *(const float4*)(&l_h[k + 4]));
    }
    l_g[q][ii] = acc;
    __syncthreads();
    if (tid < 32){
      float ig = l_g[0][tid], fg = l_g[1][tid], gg = l_g[2][tid], og = l_g[3][tid];
      float c = sigm(fg)*l_c[tid] + sigm(ig)*tanhf(gg);
      l_c[tid] = c;
      afstore(encb + ts*512 + dir*256 + w*32 + tid, sigm(og)*tanhf(c));
    }
    bar_arrive(bar, w, it+1);
    bar_wait(bar, 8, it+1);
  }
}

// K,V projections fp32 -> per-pair slot in d_out. 1024 blocks.
__global__ __launch_bounds__(256) void k_proj(
    const float* __restrict__ encA, const float* __restrict__ encB,
    const float* __restrict__ Wk, const float* __restrict__ bk,
    const float* __restrict__ Wv, const float* __restrict__ bv,
    float* outf){
  const int tid = threadIdx.x, x = blockIdx.x;
  const int role = x & 1, dc = (x >> 1) & 1, btg = x >> 2;
  const int row = dc*256 + tid;
  const float* W = (role ? Wv : Wk) + row*512;
  const float bias = (role ? bv : bk)[row];
  const int b = (btg*8) >> 7;
  const float* eb = (b < 8 ? encA : encB) + (size_t)(b & 7)*65536;
  float acc[8];
  #pragma unroll
  for (int k2 = 0; k2 < 8; ++k2) acc[k2] = bias;
  for (int e = 0; e < 512; e += 8){
    float4 wa = *(const float4*)(W + e);
    float4 wb = *(const float4*)(W + e + 4);
    #pragma unroll
    for (int k2 = 0; k2 < 8; ++k2){
      const float* ep = eb + ((btg*8 + k2) & 127)*512 + e;
      acc[k2] += dot8f(wa, wb, *(const float4*)(ep), *(const float4*)(ep + 4));
    }
  }
  const int head = row >> 6, dd = row & 63;
  float* kv = outf + (size_t)(b >> 1)*1024000 + (size_t)(b & 1)*131072;
  #pragma unroll
  for (int k2 = 0; k2 < 8; ++k2){
    const int ts = (btg*8 + k2) & 127;
    if (role == 0) kv[head*8192 + ts*64 + dd] = acc[k2];
    else           kv[65536 + head*8192 + dd*128 + ts] = acc[k2];
  }
}

// persistent decoder v11: 128 blocks = (b0, sidx) x 512 thr; batches b0 and
// b0+8 fused into one serial chain (one flag set, one poll, one drain/iter).
__global__ __launch_bounds__(512) void k_decode(
    const float* __restrict__ Wqh,   // [512][256] fp32
    const u16*   __restrict__ Wcg,   // [1024][512] bf16
    const u16*   __restrict__ W2m,   // [1024][256] bf16
    const float* __restrict__ Wmel,  // [512][256] fp32 (streamed per iter)
    const float* __restrict__ bmel,
    const float* __restrict__ Wstop, const float* __restrict__ bstop,
    const float* __restrict__ bq,    // original bq [512]
    const float* __restrict__ biasws,// bqp[512] | bg0[1024] | bgp[1024]
    float* Gbuf,                     // [3][16][768] gate accumulators (zeroed)
    float* probs, int* bars,
    float* out){                     // K/V slots alias mel region (prelude-only reads)
  const int tid = threadIdx.x;
  const int b0 = blockIdx.x & 7, sidx = blockIdx.x >> 3;   // pair, slot
  const int h = sidx >> 1, half = sidx & 1;                // head, row-half
  const int d = tid & 63, ko = tid >> 6;                   // 64 dims x 8 k-chunks
  int* bflag = bars + b0*512;          // ONE flag set covers both batches
  int* pflag = bars + (b0 ^ 1)*512;    // partner pair guard (K/V alias)
  float* out_mel  = out;
  float* out_stop = out + 8192000;
  float* out_attn = out + 8208000;

  // Strides 68/132/36 are 2-way/free for b128 (16-lane phase bank model).
  __shared__ __align__(16) float lK[2][128*68];
  __shared__ __align__(16) float lV[2][64*132];
  __shared__ __align__(16) float l_h[2][256];
  __shared__ __align__(16) float l_hw[2][288];  // staggered: chunk c at +c*36
  __shared__ __align__(16) float l_q[2][64];
  __shared__ __align__(16) float l_p[2][128];   // UNNORMALIZED exp(s-M)
  __shared__ __align__(16) float l_ct[2][64];
  __shared__ __align__(16) float l_qt[2][8][64];
  __shared__ float l_r[2];                      // S per batch

  const int rg = tid >> 2, c4 = tid & 3;        // Wcg roles
  const int rw = tid >> 3, c8 = tid & 7;        // w2m roles
  const int r2 = half*384 + h*48 + rw;          // w2m packed row

  // ---- prelude: K,V of head h for BOTH batches -> LDS ----
  #pragma unroll
  for (int s = 0; s < 2; ++s){
    const int bb = b0 + 8*s;
    const float* kvs = out + (size_t)(bb >> 1)*1024000 + (size_t)(bb & 1)*131072;
    const float* gK = kvs + h*8192;
    for (int i = tid; i < 2048; i += 512){
      const int r = i >> 4, c = i & 15;
      *(float4*)(&lK[s][r*68 + c*4]) = *(const float4*)(gK + r*64 + c*4);
    }
    const float* gV = kvs + 65536 + h*8192;
    for (int i = tid; i < 2048; i += 512){
      const int r = i >> 5, c = i & 31;
      *(float4*)(&lV[s][r*132 + c*4]) = *(const float4*)(gV + r*128 + c*4);
    }
  }

  // ---- persistent weights -> VGPRs (72/thread; batch-independent) ----
  float4 wq[8];
  {
    const float* p = Wqh + (h*64 + d)*256 + ko*32;
    #pragma unroll
    for (int j = 0; j < 8; ++j) wq[j] = *(const float4*)(p + 4*j);
  }
  uint4 wcg[3][2];
  #pragma unroll
  for (int s = 0; s < 3; ++s){
    const int r = half*384 + rg*3 + s;
    const int orig = r + (r >= 256 ? 256 : 0);   // skip dead f-rows
    const u16* p = Wcg + orig*512 + h*64 + c4*16;
    wcg[s][0] = *(const uint4*)(p);
    wcg[s][1] = *(const uint4*)(p + 8);
  }
  uint4 w2[4];
  {
    const int orig2 = r2 + (r2 >= 256 ? 256 : 0);
    const u16* p = W2m + (tid < 384 ? orig2*256 + c8*32 : 0);
    #pragma unroll
    for (int j = 0; j < 4; ++j) w2[j] = *(const uint4*)(p + 8*j);
  }
  const float bq0 = bq[h*64 + d];
  const float bq1 = biasws[h*64 + d];
  const float bmd = bmel[h*64 + half*32 + ((tid & 255) >> 3)];
  float bgi0=0, bgg0=0, bgo0=0, bgi1=0, bgg1=0, bgo1=0;
  if (tid < 256){
    bgi0 = biasws[ 512 + tid]; bgg0 = biasws[1024 + tid]; bgo0 = biasws[1280 + tid];
    bgi1 = biasws[1536 + tid]; bgg1 = biasws[2048 + tid]; bgo1 = biasws[2304 + tid];
  }
  float4 wst4 = {0.f,0.f,0.f,0.f};
  if (h == 0 && half == 1 && tid < 64) wst4 = *(const float4*)(Wstop + tid*4);
  const float bst = bstop[0];

  if (tid < 256){ l_h[0][tid] = 0.f; l_h[1][tid] = 0.f; }
  if (tid < 288){ l_hw[0][tid] = 0.f; l_hw[1][tid] = 0.f; }
  __syncthreads();

  for (int t = 0; t < 1000; ++t){
    // ---- wait: both batches' step-(t-1) reductions (one flag set) ----
    if (t >= 1) bar_wait(bflag, 16, t);
    if (t == 2) bar_wait(pflag, 16, 1);          // partner preludes done (one-time)
    // ---- issue Gbuf loads for both batches ----
    float giA=0,ggA=0,goA=0,giB=0,ggB=0,goB=0;
    if (t >= 1 && tid < 256){
      const float* bpA = Gbuf + (((t-1)%3)*16 + b0)*768;
      const float* bpB = Gbuf + (((t-1)%3)*16 + b0 + 8)*768;
      giA = afload(bpA + tid); ggA = afload(bpA + 256 + tid); goA = afload(bpA + 512 + tid);
      giB = afload(bpB + tid); ggB = afload(bpB + 256 + tid); goB = afload(bpB + 512 + tid);
    }
    // ---- mel/stop(t-2) for both batches (l_h/l_hw = h_{t-2}); covers loads ----
    if (t >= 2){
      if (tid < 256){
        const int dd = half*32 + (tid >> 3), cc = tid & 7;
        const float* pm = Wmel + (h*64 + dd)*256 + cc*32;
        #pragma unroll
        for (int s = 0; s < 2; ++s){
          const float4* hh = (const float4*)(&l_hw[s][cc*36]);
          float mp = dot8f(*(const float4*)(pm),      *(const float4*)(pm + 4),  hh[0], hh[1])
                   + dot8f(*(const float4*)(pm + 8),  *(const float4*)(pm + 12), hh[2], hh[3])
                   + dot8f(*(const float4*)(pm + 16), *(const float4*)(pm + 20), hh[4], hh[5])
                   + dot8f(*(const float4*)(pm + 24), *(const float4*)(pm + 28), hh[6], hh[7]);
          mp += __shfl_xor(mp, 1); mp += __shfl_xor(mp, 2); mp += __shfl_xor(mp, 4);
          if (cc == 0) out_mel[((size_t)(b0 + 8*s)*1000 + (t-2))*512 + h*64 + dd] = mp + bmd;
        }
      }
      if (h == 0 && half == 1 && tid < 64){
        #pragma unroll
        for (int s = 0; s < 2; ++s){
          const float4 h4v = *(const float4*)(&l_h[s][tid*4]);
          float sp = wst4.x*h4v.x + wst4.y*h4v.y + wst4.z*h4v.z + wst4.w*h4v.w;
          #pragma unroll
          for (int off = 32; off; off >>= 1) sp += __shfl_xor(sp, off);
          if (tid == 0) out_stop[(b0 + 8*s)*1000 + (t-2)] = sp + bst;
        }
      }
    }
    __syncthreads();                             // mel reads before consume writes
    // ---- consume: h_{t-1} for both batches ----
    if (t >= 1 && tid < 256){
      float gi = (t == 1 ? bgi0 : bgi1) + giA;
      float gg = (t == 1 ? bgg0 : bgg1) + ggA;
      float go = (t == 1 ? bgo0 : bgo1) + goA;
      float hv = sigm(go) * tanhf(sigm(gi) * tanhf(gg));   // c_prev == 0
      l_h[0][tid] = hv;
      l_hw[0][(tid >> 5)*36 + (tid & 31)] = hv;
      gi = (t == 1 ? bgi0 : bgi1) + giB;
      gg = (t == 1 ? bgg0 : bgg1) + ggB;
      go = (t == 1 ? bgo0 : bgo1) + goB;
      hv = sigm(go) * tanhf(sigm(gi) * tanhf(gg));
      l_h[1][tid] = hv;
      l_hw[1][(tid >> 5)*36 + (tid & 31)] = hv;
    }
    __syncthreads();
    // ---- P1: q partials + w2m aadds (both) + rot reset ----
    float* bufA = Gbuf + ((t%3)*16 + b0)*768;
    float* bufB = Gbuf + ((t%3)*16 + b0 + 8)*768;
    {
      const float4* h0v = (const float4*)(&l_h[0][ko*32]);
      const float4* h1v = (const float4*)(&l_h[1][ko*32]);
      l_qt[0][ko][d] = dot8f(wq[0], wq[1], h0v[0], h0v[1]) + dot8f(wq[2], wq[3], h0v[2], h0v[3])
                     + dot8f(wq[4], wq[5], h0v[4], h0v[5]) + dot8f(wq[6], wq[7], h0v[6], h0v[7]);
      l_qt[1][ko][d] = dot8f(wq[0], wq[1], h1v[0], h1v[1]) + dot8f(wq[2], wq[3], h1v[2], h1v[3])
                     + dot8f(wq[4], wq[5], h1v[4], h1v[5]) + dot8f(wq[6], wq[7], h1v[6], h1v[7]);
    }
    if (tid < 384){
      const float4* hh0 = (const float4*)(&l_hw[0][c8*36]);
      const float4* hh1 = (const float4*)(&l_hw[1][c8*36]);
      float wA = dot8(w2[0], hh0[0], hh0[1]) + dot8(w2[1], hh0[2], hh0[3])
               + dot8(w2[2], hh0[4], hh0[5]) + dot8(w2[3], hh0[6], hh0[7]);
      float wB = dot8(w2[0], hh1[0], hh1[1]) + dot8(w2[1], hh1[2], hh1[3])
               + dot8(w2[2], hh1[4], hh1[5]) + dot8(w2[3], hh1[6], hh1[7]);
      wA += __shfl_xor(wA, 1); wA += __shfl_xor(wA, 2); wA += __shfl_xor(wA, 4);
      wB += __shfl_xor(wB, 1); wB += __shfl_xor(wB, 2); wB += __shfl_xor(wB, 4);
      if (c8 == 0){ aadd(bufA + r2, wA); aadd(bufB + r2, wB); }
    } else if (t >= 2 && tid < 480){
      // reset step-(t-2)'s buffers (== step t+1's) for both batches; all
      // blocks read them (wait(t) passed); our arrive(t+1) drains the reset
      // before any peer's step-(t+1) writes (they wait flag t+1).
      const int li = tid - 384;                  // 0..95
      const int s2 = li >= 48, i2 = li - 48*s2;
      const int rr = (t+1)%3;
      afstore(Gbuf + (rr*16 + b0 + 8*s2)*768 + sidx*48 + i2, 0.f);
    }
    __syncthreads();
    // ---- wave0 x2: q assemble, QK^T, softmax, ctx (parallel waves) ----
    if (tid < 128){
      const int s = tid >> 6, ln = tid & 63;
      float qq = (t == 0 ? bq0 : bq1);
      #pragma unroll
      for (int k = 0; k < 8; ++k) qq += l_qt[s][k][ln];
      l_q[s][ln] = qq;
      __asm__ __volatile__("s_waitcnt lgkmcnt(0)" ::: "memory");
      const float* kr0 = &lK[s][ln*68];
      const float* kr1 = &lK[s][(ln + 64)*68];
      float s0 = 0.f, s1 = 0.f;
      #pragma unroll
      for (int k = 0; k < 64; k += 8){
        float4 qa = *(const float4*)(&l_q[s][k]), qb = *(const float4*)(&l_q[s][k + 4]);
        s0 += dot8f(*(const float4*)(kr0 + k), *(const float4*)(kr0 + k + 4), qa, qb);
        s1 += dot8f(*(const float4*)(kr1 + k), *(const float4*)(kr1 + k + 4), qa, qb);
      }
      s0 *= 0.125f; s1 *= 0.125f;
      float m = fmaxf(s0, s1);
      #pragma unroll
      for (int off = 32; off; off >>= 1) m = fmaxf(m, __shfl_xor(m, off));
      float p0 = __expf(s0 - m), p1 = __expf(s1 - m);
      float ss = p0 + p1;
      #pragma unroll
      for (int off = 32; off; off >>= 1) ss += __shfl_xor(ss, off);
      l_p[s][ln] = p0; l_p[s][ln + 64] = p1;
      __asm__ __volatile__("s_waitcnt lgkmcnt(0)" ::: "memory");
      const float* vr = &lV[s][ln*132];          // row-per-lane, 2-way free
      float cs = 0.f;
      #pragma unroll
      for (int k = 0; k < 128; k += 8)
        cs += dot8f(*(const float4*)(vr + k), *(const float4*)(vr + k + 4),
                    *(const float4*)(&l_p[s][k]), *(const float4*)(&l_p[s][k + 4]));
      l_ct[s][ln] = cs / ss;
      if (ln == 0) l_r[s] = ss;
    }
    __syncthreads();
    // ---- P5: Wcg gate partials (registers) for both -> aadd ----
    {
      const float4* ca = (const float4*)(&l_ct[0][c4*16]);
      const float4* cb = (const float4*)(&l_ct[1][c4*16]);
      float4 a0 = ca[0], a1 = ca[1], a2 = ca[2], a3 = ca[3];
      float4 e0 = cb[0], e1 = cb[1], e2 = cb[2], e3 = cb[3];
      float pA0 = dot8(wcg[0][0], a0, a1) + dot8(wcg[0][1], a2, a3);
      float pA1 = dot8(wcg[1][0], a0, a1) + dot8(wcg[1][1], a2, a3);
      float pA2 = dot8(wcg[2][0], a0, a1) + dot8(wcg[2][1], a2, a3);
      float pB0 = dot8(wcg[0][0], e0, e1) + dot8(wcg[0][1], e2, e3);
      float pB1 = dot8(wcg[1][0], e0, e1) + dot8(wcg[1][1], e2, e3);
      float pB2 = dot8(wcg[2][0], e0, e1) + dot8(wcg[2][1], e2, e3);
      pA0 += __shfl_xor(pA0, 1); pA0 += __shfl_xor(pA0, 2);
      pA1 += __shfl_xor(pA1, 1); pA1 += __shfl_xor(pA1, 2);
      pA2 += __shfl_xor(pA2, 1); pA2 += __shfl_xor(pA2, 2);
      pB0 += __shfl_xor(pB0, 1); pB0 += __shfl_xor(pB0, 2);
      pB1 += __shfl_xor(pB1, 1); pB1 += __shfl_xor(pB1, 2);
      pB2 += __shfl_xor(pB2, 1); pB2 += __shfl_xor(pB2, 2);
      if (c4 == 0){
        const int rb = half*384 + rg*3;
        aadd(bufA + rb,     pA0); aadd(bufA + rb + 1, pA1); aadd(bufA + rb + 2, pA2);
        aadd(bufB + rb,     pB0); aadd(bufB + rb + 1, pB1); aadd(bufB + rb + 2, pB2);
      }
    }
    bar_arrive(bflag, sidx, t+1);                // one drain for both batches
  }

  // ---- epilogue: consume step-999; mel/stop 998,999; probs; attn ----
  bar_wait(bflag, 16, 1000);
  float giA=0,ggA=0,goA=0,giB=0,ggB=0,goB=0;
  if (tid < 256){
    const float* bpA = Gbuf + ((999%3)*16 + b0)*768;
    const float* bpB = Gbuf + ((999%3)*16 + b0 + 8)*768;
    giA = afload(bpA + tid); ggA = afload(bpA + 256 + tid); goA = afload(bpA + 512 + tid);
    giB = afload(bpB + tid); ggB = afload(bpB + 256 + tid); goB = afload(bpB + 512 + tid);
  }
  // mel/stop(998) from h_998 (current l_h/l_hw)
  if (tid < 256){
    const int dd = half*32 + (tid >> 3), cc = tid & 7;
    const float* pm = Wmel + (h*64 + dd)*256 + cc*32;
    #pragma unroll
    for (int s = 0; s < 2; ++s){
      const float4* hh = (const float4*)(&l_hw[s][cc*36]);
      float mp = dot8f(*(const float4*)(pm),      *(const float4*)(pm + 4),  hh[0], hh[1])
               + dot8f(*(const float4*)(pm + 8),  *(const float4*)(pm + 12), hh[2], hh[3])
               + dot8f(*(const float4*)(pm + 16), *(const float4*)(pm + 20), hh[4], hh[5])
               + dot8f(*(const float4*)(pm + 24), *(const float4*)(pm + 28), hh[6], hh[7]);
      mp += __shfl_xor(mp, 1); mp += __shfl_xor(mp, 2); mp += __shfl_xor(mp, 4);
      if (cc == 0) out_mel[((size_t)(b0 + 8*s)*1000 + 998)*512 + h*64 + dd] = mp + bmd;
    }
  }
  if (h == 0 && half == 1 && tid < 64){
    #pragma unroll
    for (int s = 0; s < 2; ++s){
      const float4 h4v = *(const float4*)(&l_h[s][tid*4]);
      float sp = wst4.x*h4v.x + wst4.y*h4v.y + wst4.z*h4v.z + wst4.w*h4v.w;
      #pragma unroll
      for (int off = 32; off; off >>= 1) sp += __shfl_xor(sp, off);
      if (tid == 0) out_stop[(b0 + 8*s)*1000 + 998] = sp + bst;
    }
  }
  __syncthreads();
  if (tid < 256){   // consume -> h_999
    float gi = bgi1 + giA, gg = bgg1 + ggA, go = bgo1 + goA;
    float hv = sigm(go) * tanhf(sigm(gi) * tanhf(gg));
    l_h[0][tid] = hv; l_hw[0][(tid >> 5)*36 + (tid & 31)] = hv;
    gi = bgi1 + giB; gg = bgg1 + ggB; go = bgo1 + goB;
    hv = sigm(go) * tanhf(sigm(gi) * tanhf(gg));
    l_h[1][tid] = hv; l_hw[1][(tid >> 5)*36 + (tid & 31)] = hv;
  }
  __syncthreads();
  // mel/stop(999) from h_999
  if (tid < 256){
    const int dd = half*32 + (tid >> 3), cc = tid & 7;
    const float* pm = Wmel + (h*64 + dd)*256 + cc*32;
    #pragma unroll
    for (int s = 0; s < 2; ++s){
      const float4* hh = (const float4*)(&l_hw[s][cc*36]);
      float mp = dot8f(*(const float4*)(pm),      *(const float4*)(pm + 4),  hh[0], hh[1])
               + dot8f(*(const float4*)(pm + 8),  *(const float4*)(pm + 12), hh[2], hh[3])
               + dot8f(*(const float4*)(pm + 16), *(const float4*)(pm + 20), hh[4], hh[5])
               + dot8f(*(const float4*)(pm + 24), *(const float4*)(pm + 28), hh[6], hh[7]);
      mp += __shfl_xor(mp, 1); mp += __shfl_xor(mp, 2); mp += __shfl_xor(mp, 4);
      if (cc == 0) out_mel[((size_t)(b0 + 8*s)*1000 + 999)*512 + h*64 + dd] = mp + bmd;
    }
  }
  if (h == 0 && half == 1 && tid < 64){
    #pragma unroll
    for (int s = 0; s < 2; ++s){
      const float4 h4v = *(const float4*)(&l_h[s][tid*4]);
      float sp = wst4.x*h4v.x + wst4.y*h4v.y + wst4.z*h4v.z + wst4.w*h4v.w;
      #pragma unroll
      for (int off = 32; off; off >>= 1) sp += __shfl_xor(sp, off);
      if (tid == 0) out_stop[(b0 + 8*s)*1000 + 999] = sp + bst;
    }
  }
  if (half == 0 && tid < 128){   // l_p/l_r hold step-999 values; normalize
    afstore(probs + ((b0)*8 + h)*128 + tid,     l_p[0][tid] / l_r[0]);
    afstore(probs + ((b0 + 8)*8 + h)*128 + tid, l_p[1][tid] / l_r[1]);
  }
  bar_arrive(bflag, sidx, 1001);               // probs drained before flag
  if (h == 0 && half == 0){
    bar_wait(bflag, 16, 1001);
    if (tid < 128){
      #pragma unroll
      for (int s = 0; s < 2; ++s){
        const int bb = b0 + 8*s;
        float ssum = 0.f;
        #pragma unroll
        for (int hh = 0; hh < 8; ++hh) ssum += afload(probs + (bb*8 + hh)*128 + tid);
        out_attn[bb*128 + tid] = ssum * 0.125f;
      }
    }
  }
}

extern "C" void kernel_launch(void* const* d_in, const int* in_sizes, int n_in,
                              void* d_out, int out_size, void* d_ws, size_t ws_size,
                              hipStream_t stream){
  const int*   tok = (const int*)d_in[0];
  const int*   spk = (const int*)d_in[1];
  const float* emb_text = (const float*)d_in[2];
  const float* emb_spk  = (const float*)d_in[3];
  const float* WihF = (const float*)d_in[4];
  const float* WhhF = (const float*)d_in[5];
  const float* bihF = (const float*)d_in[6];
  const float* bhhF = (const float*)d_in[7];
  const float* WihB = (const float*)d_in[8];
  const float* WhhB = (const float*)d_in[9];
  const float* bihB = (const float*)d_in[10];
  const float* bhhB = (const float*)d_in[11];
  const float* Wq = (const float*)d_in[12];
  const float* bq = (const float*)d_in[13];
  const float* Wk = (const float*)d_in[14];
  const float* bk = (const float*)d_in[15];
  const float* Wv = (const float*)d_in[16];
  const float* bv = (const float*)d_in[17];
  const float* Wo = (const float*)d_in[18];
  const float* bo = (const float*)d_in[19];
  const float* decW = (const float*)d_in[20];
  /* d_in[21] dec_Whh dead (state re-zeroed every step) */
  const float* bih = (const float*)d_in[22];
  const float* bhh = (const float*)d_in[23];
  const float* Wmel = (const float*)d_in[24];
  const float* bmel = (const float*)d_in[25];
  const float* Wstop = (const float*)d_in[26];
  const float* bstop = (const float*)d_in[27];

  char* ws = (char*)d_ws;
  int*   bars   = (int*)(ws + WS_BAR);
  float* Gbuf   = (float*)(ws + WS_GBUF);
  float* hbuf   = (float*)(ws + WS_HBUF);
  float* probs  = (float*)(ws + WS_PROBS);
  float* biasws = (float*)(ws + WS_BIAS);
  u16*   W2m    = (u16*)(ws + WS_W2M);
  float* Wqh    = (float*)(ws + WS_WQH);
  u16*   Wcg    = (u16*)(ws + WS_WCG);

  float* outf = (float*)d_out;
  float* encA = outf + OF_ENC_A;
  float* encB = outf + OF_ENC_B;
  float* xwf  = outf + OF_XWF;
  float* xwb  = outf + OF_XWB;

  k_init <<<32,   256, 0, stream>>>(bars, hbuf);
  k_xw   <<<2048, 256, 0, stream>>>(tok, spk, emb_text, emb_spk,
                                    WihF, bihF, bhhF, WihB, bihB, bhhB, xwf, xwb);
  k_enc  <<<256,  128, 0, stream>>>(xwf, xwb, WhhF, WhhB, encA, encB, bars);
  k_fuse <<<896,  256, 0, stream>>>(decW, Wo, Wmel, Wq, Wcg, W2m, Wqh);
  k_bias <<<6,    256, 0, stream>>>(Wq, bq, bmel, decW, bo, bih, bhh, biasws);
  k_proj <<<1024, 256, 0, stream>>>(encA, encB, Wk, bk, Wv, bv, outf);
  k_decode<<<128, 512, 0, stream>>>(Wqh, Wcg, W2m, Wmel, bmel, Wstop, bstop,
                                    bq, biasws, Gbuf, probs, bars, outf);
}

// Round 11
// 7458.445 us; speedup vs baseline: 1.6611x; 1.1449x over previous
//
#include <hip/hip_runtime.h>
#include <hip/hip_bf16.h>

// TTS: embed -> BiLSTM encoder -> K/V proj -> 1000-step autoregressive decode.
// v12 decode (v9's n=1 parallelism + v11's RT-hiding schedule):
//  - v11 calibrated the step model: shared-RT ~2.3us (flag-read + drain +
//    barriers) + ~2.4us compute/batch; fusing 2 batches (n=2) improved
//    throughput/batch but WALL got worse (7.13 vs 5.70) since v9's batches
//    already ran in parallel. v12 = n=1 (256 blocks) with v11's chain order:
//      wait(t) -> issue Gbuf loads -> mel/stop(t-2) [covers Gbuf RT] ->
//      consume h_{t-1} -> P1 -> wave0 -> P5 -> arrive(t+1)
//    removing the Gbuf-read RT that v9 exposed serially in P6 (3 RTs -> 2).
//  - l_h/l_hw double-buffered (consume writes buf t&1, mel reads (t-1)&1):
//    kills the mel/consume race AND one __syncthreads (4 syncs + wait + arrive).
//  - rest = v9: 256 blocks=(b,h,half) x 512thr, 72 resident weight VGPRs,
//    ctx inside softmax wave, per-batch 768-float atomicAdd accum (rot-3,
//    reset at iter t for buffer (t+1)%3 on idle lanes, safe: flag t implies
//    all peers consumed step-(t-2)), f-gates skipped, t==2 partner guard.
// Sync: fence-free flag barriers; agent-scope RELAXED atomics. fp32 except
// bf16 Wcg/W2m. Numerics identical to v9 per batch.

typedef unsigned short u16;
typedef unsigned int   u32;
#define DI __device__ __forceinline__

// ---- ws layout (bytes) ----
static constexpr size_t WS_BAR   = 0;              // int flag lines: [0,32KB) decode, 64KB+ enc
static constexpr size_t WS_GBUF  = 64*1024;        // fp32 [3][16][768] 144KB (zeroed by k_init)
static constexpr size_t WS_HBUF  = 192*1024;       // legacy zero region
static constexpr size_t WS_PROBS = 208*1024;       // fp32 [16][8][128] 64KB
static constexpr size_t WS_BIAS  = 272*1024;       // fp32 bqp[512]|bg0[1024]|bgp[1024]
static constexpr size_t WS_W2M   = 320*1024;       // bf16 [1024][256] 512KB
static constexpr size_t WS_WQH   = 832*1024;       // fp32 [512][256]  512KB
static constexpr size_t WS_WCG   = 1344*1024;      // bf16 [1024][512] 1MB -> 2368KB

// ---- d_out scratch (float indices; d_out = 8,210,048 floats) ----
static constexpr size_t OF_ENC_A = 262144;         // fp32 [8][128][512] b=0..7
static constexpr size_t OF_ENC_B = 1286144;        // fp32 [8][128][512] b=8..15
static constexpr size_t OF_XWF   = 4015744;        // fp32 [2048][1024]
static constexpr size_t OF_XWB   = 6112896;        // fp32 [2048][1024] -> 8210048
// K/V slot (batch pair p=b>>1, sub s=b&1): outf + p*1024000 + s*131072 (K then V^T)

DI float bf2f(u16 u){ union{u32 i; float f;} v; v.i = ((u32)u)<<16; return v.f; }
DI u16 f2bf(float f){ union{float f; u32 i;} v; v.f = f;
  u32 r = v.i + 0x7fffu + ((v.i>>16)&1u); return (u16)(r>>16); }
DI float2 bf2x(u32 u){ union{u32 i; float f;} a,b; a.i = u<<16; b.i = u & 0xffff0000u;
  float2 r; r.x = a.f; r.y = b.f; return r; }
DI float dot8(uint4 wv, float4 a, float4 b){   // bf16 weights x fp32 acts
  float2 w0 = bf2x(wv.x), w1 = bf2x(wv.y), w2 = bf2x(wv.z), w3 = bf2x(wv.w);
  return w0.x*a.x + w0.y*a.y + w1.x*a.z + w1.y*a.w
       + w2.x*b.x + w2.y*b.y + w3.x*b.z + w3.y*b.w;
}
DI float dot8f(float4 wa, float4 wb, float4 a, float4 b){
  return wa.x*a.x + wa.y*a.y + wa.z*a.z + wa.w*a.w
       + wb.x*b.x + wb.y*b.y + wb.z*b.z + wb.w*b.w;
}
DI float sigm(float x){ return 1.f/(1.f + __expf(-x)); }

// agent-scope relaxed atomics: coherence-point access, no fence needed.
DI float afload(const float* p){
  return __hip_atomic_load(p, __ATOMIC_RELAXED, __HIP_MEMORY_SCOPE_AGENT);
}
DI void afstore(float* p, float v){
  __hip_atomic_store(p, v, __ATOMIC_RELAXED, __HIP_MEMORY_SCOPE_AGENT);
}
DI void aadd(float* p, float v){
  __hip_atomic_fetch_add(p, v, __ATOMIC_RELAXED, __HIP_MEMORY_SCOPE_AGENT);
}

// ---- fence-free flag barrier ----
DI void bar_arrive(int* flags, int myidx, int t){
  __syncthreads();   // each wave drains vmem at barrier (compiler vmcnt(0))
  if (threadIdx.x == 0){
    __builtin_amdgcn_s_waitcnt(0);
    __hip_atomic_store(flags + myidx*32, t, __ATOMIC_RELAXED, __HIP_MEMORY_SCOPE_AGENT);
  }
}
DI void bar_wait(int* flags, int n, int t){
  if (threadIdx.x < 64){
    const int idx = threadIdx.x & (n-1);
    int v = __hip_atomic_load(flags + idx*32, __ATOMIC_RELAXED, __HIP_MEMORY_SCOPE_AGENT);
    while (__any(v < t)){
      __builtin_amdgcn_s_sleep(1);
      if (v < t)
        v = __hip_atomic_load(flags + idx*32, __ATOMIC_RELAXED, __HIP_MEMORY_SCOPE_AGENT);
    }
  }
  __asm__ __volatile__("" ::: "memory");
  __syncthreads();
}

__global__ __launch_bounds__(256) void k_init(int* bars, float* hbuf){
  const int i = blockIdx.x*256 + threadIdx.x;   // 32 blocks
  for (int k = i; k < 49152; k += 32*256) bars[k] = 0;
  if (i < 4096) hbuf[i] = 0.f;
}

// fused embed + x@Wih.T + biases -> xw fp32. 2048 blocks.
__global__ __launch_bounds__(256) void k_xw(
    const int* __restrict__ tok, const int* __restrict__ spk,
    const float* __restrict__ et, const float* __restrict__ es,
    const float* __restrict__ WihF, const float* __restrict__ bihF, const float* __restrict__ bhhF,
    const float* __restrict__ WihB, const float* __restrict__ bihB, const float* __restrict__ bhhB,
    float* __restrict__ xwf, float* __restrict__ xwb){
  const int tid = threadIdx.x, bi = blockIdx.x;
  const int dir = bi & 1, jc = (bi >> 1) & 3, btg = bi >> 3;
  const int j = jc*256 + tid;
  const float* W = (dir ? WihB : WihF) + j*256;
  const float bias = (dir ? bihB : bihF)[j] + (dir ? bhhB : bhhF)[j];
  float* xw = dir ? xwb : xwf;

  __shared__ __align__(16) float lx[8][256];
  #pragma unroll
  for (int r = 0; r < 8; ++r){
    const int bt = btg*8 + r;
    lx[r][tid] = et[tok[bt]*256 + tid] + es[spk[bt>>7]*256 + tid];
  }
  __syncthreads();

  float acc[8];
  #pragma unroll
  for (int k2 = 0; k2 < 8; ++k2) acc[k2] = bias;
  for (int h = 0; h < 256; h += 8){
    float4 w0 = *(const float4*)(W + h);
    float4 w1 = *(const float4*)(W + h + 4);
    #pragma unroll
    for (int k2 = 0; k2 < 8; ++k2)
      acc[k2] += dot8f(w0, w1, *(const float4*)(&lx[k2][h]), *(const float4*)(&lx[k2][h+4]));
  }
  #pragma unroll
  for (int k2 = 0; k2 < 8; ++k2) xw[(btg*8 + k2)*1024 + j] = acc[k2];
}

// Wcg = W1@Wo -> bf16 [1024,512]; W2m = W2@Wmel -> bf16 [1024,256];
// Wqh = Wq@Wmel -> fp32 [512,256]. 896 blocks.
__global__ __launch_bounds__(256) void k_fuse(
    const float* __restrict__ decW, const float* __restrict__ Wo,
    const float* __restrict__ Wmel, const float* __restrict__ Wq,
    u16* __restrict__ Wcg, u16* __restrict__ W2m, float* __restrict__ Wqh){
  const int tid = threadIdx.x, blk = blockIdx.x;
  float acc[4] = {0.f,0.f,0.f,0.f};
  if (blk < 512){
    const int g0 = (blk >> 1)*4, e = (blk & 1)*256 + tid;
    for (int jj = 0; jj < 512; ++jj){
      float wo = Wo[jj*512 + e];
      #pragma unroll
      for (int i2 = 0; i2 < 4; ++i2) acc[i2] += decW[(g0+i2)*1024 + jj] * wo;
    }
    #pragma unroll
    for (int i2 = 0; i2 < 4; ++i2) Wcg[(g0+i2)*512 + e] = f2bf(acc[i2]);
  } else if (blk < 768){
    const int g0 = (blk - 512)*4, h = tid;
    for (int m = 0; m < 512; ++m){
      float wm = Wmel[m*256 + h];
      #pragma unroll
      for (int i2 = 0; i2 < 4; ++i2) acc[i2] += decW[(g0+i2)*1024 + 512 + m] * wm;
    }
    #pragma unroll
    for (int i2 = 0; i2 < 4; ++i2) W2m[(g0+i2)*256 + h] = f2bf(acc[i2]);
  } else {
    const int j0 = (blk - 768)*4, h = tid;
    for (int e = 0; e < 512; ++e){
      float wm = Wmel[e*256 + h];
      #pragma unroll
      for (int i2 = 0; i2 < 4; ++i2) acc[i2] += Wq[(j0+i2)*512 + e] * wm;
    }
    #pragma unroll
    for (int i2 = 0; i2 < 4; ++i2) Wqh[(j0+i2)*256 + h] = acc[i2];
  }
}

__global__ __launch_bounds__(256) void k_bias(
    const float* __restrict__ Wq, const float* __restrict__ bq, const float* __restrict__ bmel,
    const float* __restrict__ decW, const float* __restrict__ bo,
    const float* __restrict__ bih, const float* __restrict__ bhh, float* __restrict__ biasws){
  const int o = blockIdx.x*256 + threadIdx.x;   // 6 blocks -> 1536
  if (o < 512){
    float s = bq[o];
    for (int e = 0; e < 512; ++e) s += Wq[o*512 + e] * bmel[e];
    biasws[o] = s;                               // bq' = Wq@bmel + bq
  } else {
    const int gr = o - 512;
    float s1 = bih[gr] + bhh[gr];
    for (int jj = 0; jj < 512; ++jj) s1 += decW[gr*1024 + jj] * bo[jj];
    biasws[512 + gr] = s1;                       // bg0 = W1@bo + bih + bhh
    float s2 = s1;
    for (int m = 0; m < 512; ++m) s2 += decW[gr*1024 + 512 + m] * bmel[m];
    biasws[1536 + gr] = s2;                      // bg' = bg0 + W2@bmel
  }
}

// persistent BiLSTM encoder: 32 groups (dir,b) x 8 WGs x 128 thr. fp32.
__global__ __launch_bounds__(128) void k_enc(
    const float* __restrict__ xwf, const float* __restrict__ xwb,
    const float* __restrict__ WhhF, const float* __restrict__ WhhB,
    float* encA, float* encB, int* bars){
  const int tid = threadIdx.x;
  const int xcd = blockIdx.x & 7, sl = blockIdx.x >> 3;
  const int grp = xcd*4 + (sl >> 3);
  const int w = sl & 7;
  const int dir = grp & 1, b = grp >> 1;
  int* bar = bars + (16 + grp)*1024;
  const float* Whh = dir ? WhhB : WhhF;
  const float* xw = dir ? xwb : xwf;
  float* encb = (b < 8 ? encA : encB) + (size_t)(b & 7)*65536;
  const int q = tid >> 5, ii = tid & 31;
  const int j = q*256 + w*32 + ii;
  const float* wr = Whh + j*256;

  __shared__ __align__(16) float l_h[256];
  __shared__ float l_g[4][32];
  __shared__ float l_c[32];
  if (tid < 32) l_c[tid] = 0.f;
  __syncthreads();

  for (int it = 0; it < 128; ++it){
    const int ts = dir ? (127 - it) : it;
    float acc = xw[(b*128 + ts)*1024 + j];
    if (it > 0){
      const int tp = dir ? (ts + 1) : (ts - 1);
      const float* hp = encb + tp*512 + dir*256;
      for (int i = tid; i < 256; i += 128) l_h[i] = afload(hp + i);
      __syncthreads();
      #pragma unroll 4
      for (int k = 0; k < 256; k += 8)
        acc += dot8f(*(const float4*)(wr + k), *(const float4*)(wr + k + 4),
                     *(const float4*)(&l_h[k]), *(const float4*)(&l_h[k + 4]));
    }
    l_g[q][ii] = acc;
    __syncthreads();
    if (tid < 32){
      float ig = l_g[0][tid], fg = l_g[1][tid], gg = l_g[2][tid], og = l_g[3][tid];
      float c = sigm(fg)*l_c[tid] + sigm(ig)*tanhf(gg);
      l_c[tid] = c;
      afstore(encb + ts*512 + dir*256 + w*32 + tid, sigm(og)*tanhf(c));
    }
    bar_arrive(bar, w, it+1);
    bar_wait(bar, 8, it+1);
  }
}

// K,V projections fp32 -> per-pair slot in d_out. 1024 blocks.
__global__ __launch_bounds__(256) void k_proj(
    const float* __restrict__ encA, const float* __restrict__ encB,
    const float* __restrict__ Wk, const float* __restrict__ bk,
    const float* __restrict__ Wv, const float* __restrict__ bv,
    float* outf){
  const int tid = threadIdx.x, x = blockIdx.x;
  const int role = x & 1, dc = (x >> 1) & 1, btg = x >> 2;
  const int row = dc*256 + tid;
  const float* W = (role ? Wv : Wk) + row*512;
  const float bias = (role ? bv : bk)[row];
  const int b = (btg*8) >> 7;
  const float* eb = (b < 8 ? encA : encB) + (size_t)(b & 7)*65536;
  float acc[8];
  #pragma unroll
  for (int k2 = 0; k2 < 8; ++k2) acc[k2] = bias;
  for (int e = 0; e < 512; e += 8){
    float4 wa = *(const float4*)(W + e);
    float4 wb = *(const float4*)(W + e + 4);
    #pragma unroll
    for (int k2 = 0; k2 < 8; ++k2){
      const float* ep = eb + ((btg*8 + k2) & 127)*512 + e;
      acc[k2] += dot8f(wa, wb, *(const float4*)(ep), *(const float4*)(ep + 4));
    }
  }
  const int head = row >> 6, dd = row & 63;
  float* kv = outf + (size_t)(b >> 1)*1024000 + (size_t)(b & 1)*131072;
  #pragma unroll
  for (int k2 = 0; k2 < 8; ++k2){
    const int ts = (btg*8 + k2) & 127;
    if (role == 0) kv[head*8192 + ts*64 + dd] = acc[k2];
    else           kv[65536 + head*8192 + dd*128 + ts] = acc[k2];
  }
}

// persistent decoder v12: 256 blocks = (b,h,half) x 512 thr. Chain order:
// wait -> Gbuf loads -> mel(t-2) covers load RT -> consume -> P1 -> wave0 ->
// P5 -> arrive. l_h double-buffered. 2 exposed RTs/step (was 3 in v9).
__global__ __launch_bounds__(512) void k_decode(
    const float* __restrict__ Wqh,   // [512][256] fp32
    const u16*   __restrict__ Wcg,   // [1024][512] bf16
    const u16*   __restrict__ W2m,   // [1024][256] bf16
    const float* __restrict__ Wmel,  // [512][256] fp32 (streamed per iter)
    const float* __restrict__ bmel,
    const float* __restrict__ Wstop, const float* __restrict__ bstop,
    const float* __restrict__ bq,    // original bq [512]
    const float* __restrict__ biasws,// bqp[512] | bg0[1024] | bgp[1024]
    float* Gbuf,                     // [3][16][768] gate accumulators (zeroed)
    float* probs, int* bars,
    float* out){                     // K/V slots alias mel region (prelude-only reads)
  const int tid = threadIdx.x;
  const int b = blockIdx.x & 15, sidx = blockIdx.x >> 4;   // batch, slot
  const int h = sidx >> 1, half = sidx & 1;                // head, row-half
  const int d = tid & 63, ko = tid >> 6;                   // 64 dims x 8 k-chunks
  int* bflag = bars + b*512;
  int* pflag = bars + (b ^ 1)*512;     // partner batch guard (K/V alias)
  float* out_mel  = out;
  float* out_stop = out + 8192000;
  float* out_attn = out + 8208000;

  // Strides 68/132/36 are 2-way/free for b128 (16-lane phase bank model,
  // verified by v6/v8/v9 counters).
  __shared__ __align__(16) float lK[128*68];
  __shared__ __align__(16) float lV[64*132];
  __shared__ __align__(16) float l_h[2][256];   // double buffer: iter t writes t&1
  __shared__ __align__(16) float l_hw[2][288];  // staggered replica: chunk c at +c*36
  __shared__ __align__(16) float l_q[64];
  __shared__ __align__(16) float l_p[128];      // UNNORMALIZED exp(s-M)
  __shared__ __align__(16) float l_ct[64];      // normalized ctx
  __shared__ __align__(16) float l_qt[8][64];   // q partials
  __shared__ float l_r[2];                      // [0]=S (for epilogue probs)

  const float* kv = out + (size_t)(b >> 1)*1024000 + (size_t)(b & 1)*131072;
  const int rg = tid >> 2, c4 = tid & 3;        // Wcg roles: rows rg*3..+2, cols c4*16..+16
  const int rw = tid >> 3, c8 = tid & 7;        // w2m roles
  const int r2 = half*384 + h*48 + rw;          // w2m packed row

  // ---- prelude: K -> lK, V^T -> lV (direct f4 copies) ----
  {
    const float* gK = kv + h*8192;
    for (int i = tid; i < 2048; i += 512){
      const int r = i >> 4, c = i & 15;
      *(float4*)(lK + r*68 + c*4) = *(const float4*)(gK + r*64 + c*4);
    }
    const float* gV = kv + 65536 + h*8192;
    for (int i = tid; i < 2048; i += 512){
      const int r = i >> 5, c = i & 31;
      *(float4*)(lV + r*132 + c*4) = *(const float4*)(gV + r*128 + c*4);
    }
  }

  // ---- persistent weights -> VGPRs (72/thread; read once for 1000 steps) ----
  float4 wq[8];   // Wqh row h*64+d, cols ko*32..+32  (32 VGPR)
  {
    const float* p = Wqh + (h*64 + d)*256 + ko*32;
    #pragma unroll
    for (int j = 0; j < 8; ++j) wq[j] = *(const float4*)(p + 4*j);
  }
  uint4 wcg[3][2];   // this half's rows rg*3..+2 of {i,g,o}, cols c4*16..+16
  #pragma unroll
  for (int s = 0; s < 3; ++s){
    const int r = half*384 + rg*3 + s;           // packed row 0..767
    const int orig = r + (r >= 256 ? 256 : 0);   // skip dead f-rows
    const u16* p = Wcg + orig*512 + h*64 + c4*16;
    wcg[s][0] = *(const uint4*)(p);
    wcg[s][1] = *(const uint4*)(p + 8);
  }
  uint4 w2[4];    // W2m packed row r2, cols c8*32..+32 (tid<384; 16 VGPR)
  {
    const int orig2 = r2 + (r2 >= 256 ? 256 : 0);
    const u16* p = W2m + (tid < 384 ? orig2*256 + c8*32 : 0);
    #pragma unroll
    for (int j = 0; j < 4; ++j) w2[j] = *(const uint4*)(p + 8*j);
  }
  // biases
  const float bq0 = bq[h*64 + d];
  const float bq1 = biasws[h*64 + d];
  const float bmd = bmel[h*64 + half*32 + ((tid & 255) >> 3)];
  float bgi0=0, bgg0=0, bgo0=0, bgi1=0, bgg1=0, bgo1=0;
  if (tid < 256){
    bgi0 = biasws[ 512 + tid]; bgg0 = biasws[1024 + tid]; bgo0 = biasws[1280 + tid];
    bgi1 = biasws[1536 + tid]; bgg1 = biasws[2048 + tid]; bgo1 = biasws[2304 + tid];
  }
  float4 wst4 = {0.f,0.f,0.f,0.f};
  if (h == 0 && half == 1 && tid < 64) wst4 = *(const float4*)(Wstop + tid*4);
  const float bst = bstop[0];

  if (tid < 256) l_h[0][tid] = 0.f;             // iter 0 reads buffer 0 (h=0)
  if (tid < 288) l_hw[0][tid] = 0.f;
  __syncthreads();

  for (int t = 0; t < 1000; ++t){
    const int cur = t & 1, prv = cur ^ 1;
    // ---- wait for step-(t-1) reduction; one-time partner guard ----
    if (t >= 1) bar_wait(bflag, 16, t);
    if (t == 2) bar_wait(pflag, 16, 1);
    // ---- issue Gbuf loads (latency covered by mel/stop below) ----
    float gi = 0.f, gg = 0.f, go = 0.f;
    if (t >= 1 && tid < 256){
      const float* bp = Gbuf + (((t-1)%3)*16 + b)*768;
      gi = afload(bp + tid); gg = afload(bp + 256 + tid); go = afload(bp + 512 + tid);
    }
    // ---- mel/stop(t-2) from l_h[prv]/l_hw[prv] == h_{t-2} (no race: consume
    // writes l_h[cur]) — this work hides the Gbuf read RT ----
    if (t >= 2){
      if (tid < 256){
        const int dd = half*32 + (tid >> 3), cc = tid & 7;
        const float* pm = Wmel + (h*64 + dd)*256 + cc*32;
        const float4* hh = (const float4*)(&l_hw[prv][cc*36]);
        float mp = dot8f(*(const float4*)(pm),      *(const float4*)(pm + 4),  hh[0], hh[1])
                 + dot8f(*(const float4*)(pm + 8),  *(const float4*)(pm + 12), hh[2], hh[3])
                 + dot8f(*(const float4*)(pm + 16), *(const float4*)(pm + 20), hh[4], hh[5])
                 + dot8f(*(const float4*)(pm + 24), *(const float4*)(pm + 28), hh[6], hh[7]);
        mp += __shfl_xor(mp, 1); mp += __shfl_xor(mp, 2); mp += __shfl_xor(mp, 4);
        if (cc == 0) out_mel[((size_t)b*1000 + (t-2))*512 + h*64 + dd] = mp + bmd;
      }
      if (h == 0 && half == 1 && tid < 64){
        const float4 h4v = *(const float4*)(&l_h[prv][tid*4]);
        float sp = wst4.x*h4v.x + wst4.y*h4v.y + wst4.z*h4v.z + wst4.w*h4v.w;
        #pragma unroll
        for (int off = 32; off; off >>= 1) sp += __shfl_xor(sp, off);
        if (tid == 0) out_stop[b*1000 + (t-2)] = sp + bst;
      }
    }
    // ---- consume: h_{t-1} -> l_h[cur] (loads complete under mel) ----
    if (t >= 1 && tid < 256){
      float gI = (t == 1 ? bgi0 : bgi1) + gi;
      float gG = (t == 1 ? bgg0 : bgg1) + gg;
      float gO = (t == 1 ? bgo0 : bgo1) + go;
      float hv = sigm(gO) * tanhf(sigm(gI) * tanhf(gG));   // c_prev == 0
      l_h[cur][tid] = hv;
      l_hw[cur][(tid >> 5)*36 + (tid & 31)] = hv;
    }
    __syncthreads();
    // ---- P1: q partials + w2m aadds + rot reset ----
    float* buf = Gbuf + ((t%3)*16 + b)*768;
    {
      const float4* hh = (const float4*)(&l_h[cur][ko*32]);
      l_qt[ko][d] = dot8f(wq[0], wq[1], hh[0], hh[1]) + dot8f(wq[2], wq[3], hh[2], hh[3])
                  + dot8f(wq[4], wq[5], hh[4], hh[5]) + dot8f(wq[6], wq[7], hh[6], hh[7]);
    }
    if (tid < 384){
      const float4* hh = (const float4*)(&l_hw[cur][c8*36]);
      float w2p = dot8(w2[0], hh[0], hh[1]) + dot8(w2[1], hh[2], hh[3])
                + dot8(w2[2], hh[4], hh[5]) + dot8(w2[3], hh[6], hh[7]);
      w2p += __shfl_xor(w2p, 1);
      w2p += __shfl_xor(w2p, 2);
      w2p += __shfl_xor(w2p, 4);               // combine 8 col-chunks
      if (c8 == 0) aadd(buf + r2, w2p);
    } else if (t >= 2 && tid >= 432 && tid < 480){
      // reset step-(t-2)'s buffer (== step t+1's): flag t implies all peers
      // consumed it at their iter t-1; our arrive(t+1) drains this store
      // before any peer's step-(t+1) writes (they wait flag t+1).
      const int rr = (t+1)%3;
      afstore(Gbuf + (rr*16 + b)*768 + sidx*48 + (tid - 432), 0.f);
    }
    __syncthreads();
    // ---- wave0: q assemble, QK^T, softmax, ctx — no internal barriers ----
    if (tid < 64){
      float qq = (t == 0 ? bq0 : bq1);
      #pragma unroll
      for (int k = 0; k < 8; ++k) qq += l_qt[k][tid];
      l_q[tid] = qq;
      __asm__ __volatile__("s_waitcnt lgkmcnt(0)" ::: "memory");
      const float* kr0 = lK + tid*68;
      const float* kr1 = lK + (tid + 64)*68;
      float s0 = 0.f, s1 = 0.f;
      #pragma unroll
      for (int k = 0; k < 64; k += 8){
        float4 qa = *(const float4*)(l_q + k), qb = *(const float4*)(l_q + k + 4);
        s0 += dot8f(*(const float4*)(kr0 + k), *(const float4*)(kr0 + k + 4), qa, qb);
        s1 += dot8f(*(const float4*)(kr1 + k), *(const float4*)(kr1 + k + 4), qa, qb);
      }
      s0 *= 0.125f; s1 *= 0.125f;
      float m = fmaxf(s0, s1);
      #pragma unroll
      for (int off = 32; off; off >>= 1) m = fmaxf(m, __shfl_xor(m, off));
      float p0 = __expf(s0 - m), p1 = __expf(s1 - m);
      float ss = p0 + p1;
      #pragma unroll
      for (int off = 32; off; off >>= 1) ss += __shfl_xor(ss, off);
      l_p[tid] = p0; l_p[tid + 64] = p1;
      __asm__ __volatile__("s_waitcnt lgkmcnt(0)" ::: "memory");
      const float* vr = lV + tid*132;            // row-per-lane, 2-way free
      float cs = 0.f;
      #pragma unroll
      for (int k = 0; k < 128; k += 8)
        cs += dot8f(*(const float4*)(vr + k), *(const float4*)(vr + k + 4),
                    *(const float4*)(l_p + k), *(const float4*)(l_p + k + 4));
      l_ct[tid] = cs / ss;
      if (tid == 0) l_r[0] = ss;
    }
    __syncthreads();
    // ---- P5: Wcg gate partials (registers) -> per-batch aadd ----
    {
      const float4* ct = (const float4*)(l_ct + c4*16);
      float4 c0 = ct[0], c1 = ct[1], c2 = ct[2], c3 = ct[3];
      float pr0 = dot8(wcg[0][0], c0, c1) + dot8(wcg[0][1], c2, c3);
      float pr1 = dot8(wcg[1][0], c0, c1) + dot8(wcg[1][1], c2, c3);
      float pr2 = dot8(wcg[2][0], c0, c1) + dot8(wcg[2][1], c2, c3);
      pr0 += __shfl_xor(pr0, 1); pr0 += __shfl_xor(pr0, 2);
      pr1 += __shfl_xor(pr1, 1); pr1 += __shfl_xor(pr1, 2);
      pr2 += __shfl_xor(pr2, 1); pr2 += __shfl_xor(pr2, 2);
      if (c4 == 0){
        const int rb = half*384 + rg*3;
        aadd(buf + rb,     pr0);
        aadd(buf + rb + 1, pr1);
        aadd(buf + rb + 2, pr2);
      }
    }
    bar_arrive(bflag, sidx, t+1);                // drains adds + reset, then flag
  }

  // ---- epilogue: consume step-999; mel/stop 998,999; probs; attn ----
  // after loop: l_h[1] == h_998 (written at iter 999); l_p/l_r hold step 999.
  bar_wait(bflag, 16, 1000);
  float gi = 0.f, gg = 0.f, go = 0.f;
  if (tid < 256){
    const float* bp = Gbuf + ((999%3)*16 + b)*768;
    gi = afload(bp + tid); gg = afload(bp + 256 + tid); go = afload(bp + 512 + tid);
  }
  // mel/stop(998) from h_998 (buffer 1); consume writes buffer 0 (no race)
  if (tid < 256){
    const int dd = half*32 + (tid >> 3), cc = tid & 7;
    const float* pm = Wmel + (h*64 + dd)*256 + cc*32;
    const float4* hh = (const float4*)(&l_hw[1][cc*36]);
    float mp = dot8f(*(const float4*)(pm),      *(const float4*)(pm + 4),  hh[0], hh[1])
             + dot8f(*(const float4*)(pm + 8),  *(const float4*)(pm + 12), hh[2], hh[3])
             + dot8f(*(const float4*)(pm + 16), *(const float4*)(pm + 20), hh[4], hh[5])
             + dot8f(*(const float4*)(pm + 24), *(const float4*)(pm + 28), hh[6], hh[7]);
    mp += __shfl_xor(mp, 1); mp += __shfl_xor(mp, 2); mp += __shfl_xor(mp, 4);
    if (cc == 0) out_mel[((size_t)b*1000 + 998)*512 + h*64 + dd] = mp + bmd;
  }
  if (h == 0 && half == 1 && tid < 64){
    const float4 h4v = *(const float4*)(&l_h[1][tid*4]);
    float sp = wst4.x*h4v.x + wst4.y*h4v.y + wst4.z*h4v.z + wst4.w*h4v.w;
    #pragma unroll
    for (int off = 32; off; off >>= 1) sp += __shfl_xor(sp, off);
    if (tid == 0) out_stop[b*1000 + 998] = sp + bst;
  }
  if (tid < 256){   // consume -> h_999 into buffer 0
    float gI = bgi1 + gi, gG = bgg1 + gg, gO = bgo1 + go;
    float hv = sigm(gO) * tanhf(sigm(gI) * tanhf(gG));
    l_h[0][tid] = hv;
    l_hw[0][(tid >> 5)*36 + (tid & 31)] = hv;
  }
  __syncthreads();
  // mel/stop(999) from h_999
  if (tid < 256){
    const int dd = half*32 + (tid >> 3), cc = tid & 7;
    const float* pm = Wmel + (h*64 + dd)*256 + cc*32;
    const float4* hh = (const float4*)(&l_hw[0][cc*36]);
    float mp = dot8f(*(const float4*)(pm),      *(const float4*)(pm + 4),  hh[0], hh[1])
             + dot8f(*(const float4*)(pm + 8),  *(const float4*)(pm + 12), hh[2], hh[3])
             + dot8f(*(const float4*)(pm + 16), *(const float4*)(pm + 20), hh[4], hh[5])
             + dot8f(*(const float4*)(pm + 24), *(const float4*)(pm + 28), hh[6], hh[7]);
    mp += __shfl_xor(mp, 1); mp += __shfl_xor(mp, 2); mp += __shfl_xor(mp, 4);
    if (cc == 0) out_mel[((size_t)b*1000 + 999)*512 + h*64 + dd] = mp + bmd;
  }
  if (h == 0 && half == 1 && tid < 64){
    const float4 h4v = *(const float4*)(&l_h[0][tid*4]);
    float sp = wst4.x*h4v.x + wst4.y*h4v.y + wst4.z*h4v.z + wst4.w*h4v.w;
    #pragma unroll
    for (int off = 32; off; off >>= 1) sp += __shfl_xor(sp, off);
    if (tid == 0) out_stop[b*1000 + 999] = sp + bst;
  }
  if (half == 0 && tid < 128)   // l_p/l_r hold step-999 values; normalize here
    afstore(probs + (b*8 + h)*128 + tid, l_p[tid] / l_r[0]);
  bar_arrive(bflag, sidx, 1001);                 // probs drained before flag
  if (h == 0 && half == 0){
    bar_wait(bflag, 16, 1001);
    if (tid < 128){
      float ssum = 0.f;
      #pragma unroll
      for (int hh = 0; hh < 8; ++hh) ssum += afload(probs + (b*8 + hh)*128 + tid);
      out_attn[b*128 + tid] = ssum * 0.125f;
    }
  }
}

extern "C" void kernel_launch(void* const* d_in, const int* in_sizes, int n_in,
                              void* d_out, int out_size, void* d_ws, size_t ws_size,
                              hipStream_t stream){
  const int*   tok = (const int*)d_in[0];
  const int*   spk = (const int*)d_in[1];
  const float* emb_text = (const float*)d_in[2];
  const float* emb_spk  = (const float*)d_in[3];
  const float* WihF = (const float*)d_in[4];
  const float* WhhF = (const float*)d_in[5];
  const float* bihF = (const float*)d_in[6];
  const float* bhhF = (const float*)d_in[7];
  const float* WihB = (const float*)d_in[8];
  const float* WhhB = (const float*)d_in[9];
  const float* bihB = (const float*)d_in[10];
  const float* bhhB = (const float*)d_in[11];
  const float* Wq = (const float*)d_in[12];
  const float* bq = (const float*)d_in[13];
  const float* Wk = (const float*)d_in[14];
  const float* bk = (const float*)d_in[15];
  const float* Wv = (const float*)d_in[16];
  const float* bv = (const float*)d_in[17];
  const float* Wo = (const float*)d_in[18];
  const float* bo = (const float*)d_in[19];
  const float* decW = (const float*)d_in[20];
  /* d_in[21] dec_Whh dead (state re-zeroed every step) */
  const float* bih = (const float*)d_in[22];
  const float* bhh = (const float*)d_in[23];
  const float* Wmel = (const float*)d_in[24];
  const float* bmel = (const float*)d_in[25];
  const float* Wstop = (const float*)d_in[26];
  const float* bstop = (const float*)d_in[27];

  char* ws = (char*)d_ws;
  int*   bars   = (int*)(ws + WS_BAR);
  float* Gbuf   = (float*)(ws + WS_GBUF);
  float* hbuf   = (float*)(ws + WS_HBUF);
  float* probs  = (float*)(ws + WS_PROBS);
  float* biasws = (float*)(ws + WS_BIAS);
  u16*   W2m    = (u16*)(ws + WS_W2M);
  float* Wqh    = (float*)(ws + WS_WQH);
  u16*   Wcg    = (u16*)(ws + WS_WCG);

  float* outf = (float*)d_out;
  float* encA = outf + OF_ENC_A;
  float* encB = outf + OF_ENC_B;
  float* xwf  = outf + OF_XWF;
  float* xwb  = outf + OF_XWB;

  k_init <<<32,   256, 0, stream>>>(bars, hbuf);
  k_xw   <<<2048, 256, 0, stream>>>(tok, spk, emb_text, emb_spk,
                                    WihF, bihF, bhhF, WihB, bihB, bhhB, xwf, xwb);
  k_enc  <<<256,  128, 0, stream>>>(xwf, xwb, WhhF, WhhB, encA, encB, bars);
  k_fuse <<<896,  256, 0, stream>>>(decW, Wo, Wmel, Wq, Wcg, W2m, Wqh);
  k_bias <<<6,    256, 0, stream>>>(Wq, bq, bmel, decW, bo, bih, bhh, biasws);
  k_proj <<<1024, 256, 0, stream>>>(encA, encB, Wk, bk, Wv, bv, outf);
  k_decode<<<256, 512, 0, stream>>>(Wqh, Wcg, W2m, Wmel, bmel, Wstop, bstop,
                                    bq, biasws, Gbuf, probs, bars, outf);
}

// Round 13
// 6616.594 us; speedup vs baseline: 1.8724x; 1.1272x over previous
//
#include <hip/hip_runtime.h>
#include <hip/hip_bf16.h>

// TTS: embed -> BiLSTM encoder -> K/V proj -> 1000-step autoregressive decode.
// v13 == v9 (session-best; round-12 bench failed on container infra, resubmit):
//  - Five structurally distinct decode schedules (v6 6-sync, v7/v8 WV-precomp,
//    v9 4-sync, v10 two-batch interleave, v12 RT-reorder) all land at
//    5.7±0.3us/step. The step is pinned by the serial chain of a 16-block
//    cross-XCD reduction through the LLC coherence point: flag-poll RT
//    (~1us, partially hidden under gap-mel) + Gbuf coherent read (~0.9us)
//    + atomicAdd drain (~0.9us) + ~2.2us VALU + barriers. v10 proved slack
//    elsewhere doesn't help (phase interleave: 0 gain); v12 proved swapping
//    which RT is hidden loses (6.31 vs 5.70). Latency floor, not BW/compute.
//  - Structure: 256 blocks = (b,h,half) x 512 thr; 72 resident weight VGPRs
//    (wq32 fp32 + wcg24 bf16 + w2m16 bf16; v6-proven 124-reg fit); ctx
//    computed inside the softmax wave (row-per-lane lV, 2-way bank = free);
//    ONE RT/step: per-batch 768-float atomicAdd accum (rot-3, reset 2 steps
//    behind), flag barrier (16 arrivals), redundant h_t everywhere; f-gates
//    skipped (c_prev==0); gap-mel/stop hidden under the flag wait; t==1
//    partner wait guards mel vs K/V-slot alias.
// Sync: fence-free flag barriers; agent-scope RELAXED atomics. fp32 except
// bf16 Wcg/W2m.

typedef unsigned short u16;
typedef unsigned int   u32;
#define DI __device__ __forceinline__

// ---- ws layout (bytes) ----
static constexpr size_t WS_BAR   = 0;              // int flag lines: [0,32KB) decode, 64KB+ enc
static constexpr size_t WS_GBUF  = 64*1024;        // fp32 [3][16][768] 144KB (zeroed by k_init)
static constexpr size_t WS_HBUF  = 192*1024;       // legacy zero region
static constexpr size_t WS_PROBS = 208*1024;       // fp32 [16][8][128] 64KB
static constexpr size_t WS_BIAS  = 272*1024;       // fp32 bqp[512]|bg0[1024]|bgp[1024]
static constexpr size_t WS_W2M   = 320*1024;       // bf16 [1024][256] 512KB
static constexpr size_t WS_WQH   = 832*1024;       // fp32 [512][256]  512KB
static constexpr size_t WS_WCG   = 1344*1024;      // bf16 [1024][512] 1MB -> 2368KB

// ---- d_out scratch (float indices; d_out = 8,210,048 floats) ----
static constexpr size_t OF_ENC_A = 262144;         // fp32 [8][128][512] b=0..7
static constexpr size_t OF_ENC_B = 1286144;        // fp32 [8][128][512] b=8..15
static constexpr size_t OF_XWF   = 4015744;        // fp32 [2048][1024]
static constexpr size_t OF_XWB   = 6112896;        // fp32 [2048][1024] -> 8210048
// K/V slot (batch pair p=b>>1, sub s=b&1): outf + p*1024000 + s*131072 (K then V^T)

DI float bf2f(u16 u){ union{u32 i; float f;} v; v.i = ((u32)u)<<16; return v.f; }
DI u16 f2bf(float f){ union{float f; u32 i;} v; v.f = f;
  u32 r = v.i + 0x7fffu + ((v.i>>16)&1u); return (u16)(r>>16); }
DI float2 bf2x(u32 u){ union{u32 i; float f;} a,b; a.i = u<<16; b.i = u & 0xffff0000u;
  float2 r; r.x = a.f; r.y = b.f; return r; }
DI float dot8(uint4 wv, float4 a, float4 b){   // bf16 weights x fp32 acts
  float2 w0 = bf2x(wv.x), w1 = bf2x(wv.y), w2 = bf2x(wv.z), w3 = bf2x(wv.w);
  return w0.x*a.x + w0.y*a.y + w1.x*a.z + w1.y*a.w
       + w2.x*b.x + w2.y*b.y + w3.x*b.z + w3.y*b.w;
}
DI float dot8f(float4 wa, float4 wb, float4 a, float4 b){
  return wa.x*a.x + wa.y*a.y + wa.z*a.z + wa.w*a.w
       + wb.x*b.x + wb.y*b.y + wb.z*b.z + wb.w*b.w;
}
DI float sigm(float x){ return 1.f/(1.f + __expf(-x)); }

// agent-scope relaxed atomics: coherence-point access, no fence needed.
DI float afload(const float* p){
  return __hip_atomic_load(p, __ATOMIC_RELAXED, __HIP_MEMORY_SCOPE_AGENT);
}
DI void afstore(float* p, float v){
  __hip_atomic_store(p, v, __ATOMIC_RELAXED, __HIP_MEMORY_SCOPE_AGENT);
}
DI void aadd(float* p, float v){
  __hip_atomic_fetch_add(p, v, __ATOMIC_RELAXED, __HIP_MEMORY_SCOPE_AGENT);
}

// ---- fence-free flag barrier ----
DI void bar_arrive(int* flags, int myidx, int t){
  __syncthreads();
  if (threadIdx.x == 0){
    __builtin_amdgcn_s_waitcnt(0);
    __hip_atomic_store(flags + myidx*32, t, __ATOMIC_RELAXED, __HIP_MEMORY_SCOPE_AGENT);
  }
}
DI void bar_wait(int* flags, int n, int t){
  if (threadIdx.x < 64){
    const int idx = threadIdx.x & (n-1);
    int v = __hip_atomic_load(flags + idx*32, __ATOMIC_RELAXED, __HIP_MEMORY_SCOPE_AGENT);
    while (__any(v < t)){
      __builtin_amdgcn_s_sleep(1);
      if (v < t)
        v = __hip_atomic_load(flags + idx*32, __ATOMIC_RELAXED, __HIP_MEMORY_SCOPE_AGENT);
    }
  }
  __asm__ __volatile__("" ::: "memory");
  __syncthreads();
}

__global__ __launch_bounds__(256) void k_init(int* bars, float* hbuf){
  const int i = blockIdx.x*256 + threadIdx.x;   // 32 blocks
  for (int k = i; k < 49152; k += 32*256) bars[k] = 0;
  if (i < 4096) hbuf[i] = 0.f;
}

// fused embed + x@Wih.T + biases -> xw fp32. 2048 blocks.
__global__ __launch_bounds__(256) void k_xw(
    const int* __restrict__ tok, const int* __restrict__ spk,
    const float* __restrict__ et, const float* __restrict__ es,
    const float* __restrict__ WihF, const float* __restrict__ bihF, const float* __restrict__ bhhF,
    const float* __restrict__ WihB, const float* __restrict__ bihB, const float* __restrict__ bhhB,
    float* __restrict__ xwf, float* __restrict__ xwb){
  const int tid = threadIdx.x, bi = blockIdx.x;
  const int dir = bi & 1, jc = (bi >> 1) & 3, btg = bi >> 3;
  const int j = jc*256 + tid;
  const float* W = (dir ? WihB : WihF) + j*256;
  const float bias = (dir ? bihB : bihF)[j] + (dir ? bhhB : bhhF)[j];
  float* xw = dir ? xwb : xwf;

  __shared__ __align__(16) float lx[8][256];
  #pragma unroll
  for (int r = 0; r < 8; ++r){
    const int bt = btg*8 + r;
    lx[r][tid] = et[tok[bt]*256 + tid] + es[spk[bt>>7]*256 + tid];
  }
  __syncthreads();

  float acc[8];
  #pragma unroll
  for (int k2 = 0; k2 < 8; ++k2) acc[k2] = bias;
  for (int h = 0; h < 256; h += 8){
    float4 w0 = *(const float4*)(W + h);
    float4 w1 = *(const float4*)(W + h + 4);
    #pragma unroll
    for (int k2 = 0; k2 < 8; ++k2)
      acc[k2] += dot8f(w0, w1, *(const float4*)(&lx[k2][h]), *(const float4*)(&lx[k2][h+4]));
  }
  #pragma unroll
  for (int k2 = 0; k2 < 8; ++k2) xw[(btg*8 + k2)*1024 + j] = acc[k2];
}

// Wcg = W1@Wo -> bf16 [1024,512]; W2m = W2@Wmel -> bf16 [1024,256];
// Wqh = Wq@Wmel -> fp32 [512,256]. 896 blocks.
__global__ __launch_bounds__(256) void k_fuse(
    const float* __restrict__ decW, const float* __restrict__ Wo,
    const float* __restrict__ Wmel, const float* __restrict__ Wq,
    u16* __restrict__ Wcg, u16* __restrict__ W2m, float* __restrict__ Wqh){
  const int tid = threadIdx.x, blk = blockIdx.x;
  float acc[4] = {0.f,0.f,0.f,0.f};
  if (blk < 512){
    const int g0 = (blk >> 1)*4, e = (blk & 1)*256 + tid;
    for (int jj = 0; jj < 512; ++jj){
      float wo = Wo[jj*512 + e];
      #pragma unroll
      for (int i2 = 0; i2 < 4; ++i2) acc[i2] += decW[(g0+i2)*1024 + jj] * wo;
    }
    #pragma unroll
    for (int i2 = 0; i2 < 4; ++i2) Wcg[(g0+i2)*512 + e] = f2bf(acc[i2]);
  } else if (blk < 768){
    const int g0 = (blk - 512)*4, h = tid;
    for (int m = 0; m < 512; ++m){
      float wm = Wmel[m*256 + h];
      #pragma unroll
      for (int i2 = 0; i2 < 4; ++i2) acc[i2] += decW[(g0+i2)*1024 + 512 + m] * wm;
    }
    #pragma unroll
    for (int i2 = 0; i2 < 4; ++i2) W2m[(g0+i2)*256 + h] = f2bf(acc[i2]);
  } else {
    const int j0 = (blk - 768)*4, h = tid;
    for (int e = 0; e < 512; ++e){
      float wm = Wmel[e*256 + h];
      #pragma unroll
      for (int i2 = 0; i2 < 4; ++i2) acc[i2] += Wq[(j0+i2)*512 + e] * wm;
    }
    #pragma unroll
    for (int i2 = 0; i2 < 4; ++i2) Wqh[(j0+i2)*256 + h] = acc[i2];
  }
}

__global__ __launch_bounds__(256) void k_bias(
    const float* __restrict__ Wq, const float* __restrict__ bq, const float* __restrict__ bmel,
    const float* __restrict__ decW, const float* __restrict__ bo,
    const float* __restrict__ bih, const float* __restrict__ bhh, float* __restrict__ biasws){
  const int o = blockIdx.x*256 + threadIdx.x;   // 6 blocks -> 1536
  if (o < 512){
    float s = bq[o];
    for (int e = 0; e < 512; ++e) s += Wq[o*512 + e] * bmel[e];
    biasws[o] = s;                               // bq' = Wq@bmel + bq
  } else {
    const int gr = o - 512;
    float s1 = bih[gr] + bhh[gr];
    for (int jj = 0; jj < 512; ++jj) s1 += decW[gr*1024 + jj] * bo[jj];
    biasws[512 + gr] = s1;                       // bg0 = W1@bo + bih + bhh
    float s2 = s1;
    for (int m = 0; m < 512; ++m) s2 += decW[gr*1024 + 512 + m] * bmel[m];
    biasws[1536 + gr] = s2;                      // bg' = bg0 + W2@bmel
  }
}

// persistent BiLSTM encoder: 32 groups (dir,b) x 8 WGs x 128 thr. fp32.
__global__ __launch_bounds__(128) void k_enc(
    const float* __restrict__ xwf, const float* __restrict__ xwb,
    const float* __restrict__ WhhF, const float* __restrict__ WhhB,
    float* encA, float* encB, int* bars){
  const int tid = threadIdx.x;
  const int xcd = blockIdx.x & 7, sl = blockIdx.x >> 3;
  const int grp = xcd*4 + (sl >> 3);
  const int w = sl & 7;
  const int dir = grp & 1, b = grp >> 1;
  int* bar = bars + (16 + grp)*1024;
  const float* Whh = dir ? WhhB : WhhF;
  const float* xw = dir ? xwb : xwf;
  float* encb = (b < 8 ? encA : encB) + (size_t)(b & 7)*65536;
  const int q = tid >> 5, ii = tid & 31;
  const int j = q*256 + w*32 + ii;
  const float* wr = Whh + j*256;

  __shared__ __align__(16) float l_h[256];
  __shared__ float l_g[4][32];
  __shared__ float l_c[32];
  if (tid < 32) l_c[tid] = 0.f;
  __syncthreads();

  for (int it = 0; it < 128; ++it){
    const int ts = dir ? (127 - it) : it;
    float acc = xw[(b*128 + ts)*1024 + j];
    if (it > 0){
      const int tp = dir ? (ts + 1) : (ts - 1);
      const float* hp = encb + tp*512 + dir*256;
      for (int i = tid; i < 256; i += 128) l_h[i] = afload(hp + i);
      __syncthreads();
      #pragma unroll 4
      for (int k = 0; k < 256; k += 8)
        acc += dot8f(*(const float4*)(wr + k), *(const float4*)(wr + k + 4),
                     *(const float4*)(&l_h[k]), *(const float4*)(&l_h[k + 4]));
    }
    l_g[q][ii] = acc;
    __syncthreads();
    if (tid < 32){
      float ig = l_g[0][tid], fg = l_g[1][tid], gg = l_g[2][tid], og = l_g[3][tid];
      float c = sigm(fg)*l_c[tid] + sigm(ig)*tanhf(gg);
      l_c[tid] = c;
      afstore(encb + ts*512 + dir*256 + w*32 + tid, sigm(og)*tanhf(c));
    }
    bar_arrive(bar, w, it+1);
    bar_wait(bar, 8, it+1);
  }
}

// K,V projections fp32 -> per-pair slot in d_out. 1024 blocks.
__global__ __launch_bounds__(256) void k_proj(
    const float* __restrict__ encA, const float* __restrict__ encB,
    const float* __restrict__ Wk, const float* __restrict__ bk,
    const float* __restrict__ Wv, const float* __restrict__ bv,
    float* outf){
  const int tid = threadIdx.x, x = blockIdx.x;
  const int role = x & 1, dc = (x >> 1) & 1, btg = x >> 2;
  const int row = dc*256 + tid;
  const float* W = (role ? Wv : Wk) + row*512;
  const float bias = (role ? bv : bk)[row];
  const int b = (btg*8) >> 7;
  const float* eb = (b < 8 ? encA : encB) + (size_t)(b & 7)*65536;
  float acc[8];
  #pragma unroll
  for (int k2 = 0; k2 < 8; ++k2) acc[k2] = bias;
  for (int e = 0; e < 512; e += 8){
    float4 wa = *(const float4*)(W + e);
    float4 wb = *(const float4*)(W + e + 4);
    #pragma unroll
    for (int k2 = 0; k2 < 8; ++k2){
      const float* ep = eb + ((btg*8 + k2) & 127)*512 + e;
      acc[k2] += dot8f(wa, wb, *(const float4*)(ep), *(const float4*)(ep + 4));
    }
  }
  const int head = row >> 6, dd = row & 63;
  float* kv = outf + (size_t)(b >> 1)*1024000 + (size_t)(b & 1)*131072;
  #pragma unroll
  for (int k2 = 0; k2 < 8; ++k2){
    const int ts = (btg*8 + k2) & 127;
    if (role == 0) kv[head*8192 + ts*64 + dd] = acc[k2];
    else           kv[65536 + head*8192 + dd*128 + ts] = acc[k2];
  }
}

// persistent decoder (v9 structure): 256 blocks = (b,h,half) x 512 thr. ctx
// computed in the softmax wave; Wcg in regs; one RT/step; sync-free mel gap.
__global__ __launch_bounds__(512) void k_decode(
    const float* __restrict__ Wqh,   // [512][256] fp32
    const u16*   __restrict__ Wcg,   // [1024][512] bf16
    const u16*   __restrict__ W2m,   // [1024][256] bf16
    const float* __restrict__ Wmel,  // [512][256] fp32 (streamed per step)
    const float* __restrict__ bmel,
    const float* __restrict__ Wstop, const float* __restrict__ bstop,
    const float* __restrict__ bq,    // original bq [512]
    const float* __restrict__ biasws,// bqp[512] | bg0[1024] | bgp[1024]
    float* Gbuf,                     // [3][16][768] gate accumulators (zeroed)
    float* probs, int* bars,
    float* out){                     // K/V slots alias mel region (prelude-only reads)
  const int tid = threadIdx.x;
  const int b = blockIdx.x & 15, sidx = blockIdx.x >> 4;   // batch, slot
  const int h = sidx >> 1, half = sidx & 1;                // head, row-half
  const int d = tid & 63, ko = tid >> 6;                   // 64 dims x 8 k-chunks
  int* bflag = bars + b*512;
  float* out_mel  = out;
  float* out_stop = out + 8192000;
  float* out_attn = out + 8208000;

  // lK: fp32 [128][68]; lV: fp32 [64][132] — both strides 2-way/free for b128
  // (16-lane phase bank model, verified by v6/v8 counters).
  __shared__ __align__(16) float lK[128*68];
  __shared__ __align__(16) float lV[64*132];
  __shared__ __align__(16) float l_h[256];
  __shared__ __align__(16) float l_hw[8*36];    // staggered replica: chunk c at l_hw+c*36
  __shared__ __align__(16) float l_q[64];
  __shared__ __align__(16) float l_p[128];      // UNNORMALIZED exp(s-M)
  __shared__ __align__(16) float l_ct[64];      // normalized ctx
  __shared__ __align__(16) float l_qt[8][64];   // q partials
  __shared__ float l_r[2];                      // [0]=S (for epilogue probs)

  const float* kv = out + (size_t)(b >> 1)*1024000 + (size_t)(b & 1)*131072;
  const int rg = tid >> 2, c4 = tid & 3;        // Wcg roles: rows rg*3..+2, cols c4*16..+16
  const int rw = tid >> 3, c8 = tid & 7;        // w2m roles
  const int r2 = half*384 + h*48 + rw;          // w2m packed row

  // ---- prelude: K -> lK, V^T -> lV (direct f4 copies) ----
  {
    const float* gK = kv + h*8192;
    for (int i = tid; i < 2048; i += 512){
      const int r = i >> 4, c = i & 15;
      *(float4*)(lK + r*68 + c*4) = *(const float4*)(gK + r*64 + c*4);
    }
    const float* gV = kv + 65536 + h*8192;
    for (int i = tid; i < 2048; i += 512){
      const int r = i >> 5, c = i & 31;
      *(float4*)(lV + r*132 + c*4) = *(const float4*)(gV + r*128 + c*4);
    }
  }

  // ---- persistent weights -> VGPRs (72/thread; read once for 1000 steps) ----
  float4 wq[8];   // Wqh row h*64+d, cols ko*32..+32  (32 VGPR)
  {
    const float* p = Wqh + (h*64 + d)*256 + ko*32;
    #pragma unroll
    for (int j = 0; j < 8; ++j) wq[j] = *(const float4*)(p + 4*j);
  }
  // Wcg: this half's 384 packed rows {i,g,o}\f, head cols h*64..+64 (24 VGPR)
  uint4 wcg[3][2];
  #pragma unroll
  for (int s = 0; s < 3; ++s){
    const int r = half*384 + rg*3 + s;           // packed row 0..767
    const int orig = r + (r >= 256 ? 256 : 0);   // skip dead f-rows
    const u16* p = Wcg + orig*512 + h*64 + c4*16;
    wcg[s][0] = *(const uint4*)(p);
    wcg[s][1] = *(const uint4*)(p + 8);
  }
  uint4 w2[4];    // W2m packed row r2, cols c8*32..+32 (tid<384; 16 VGPR)
  {
    const int orig2 = r2 + (r2 >= 256 ? 256 : 0);
    const u16* p = W2m + (tid < 384 ? orig2*256 + c8*32 : 0);
    #pragma unroll
    for (int j = 0; j < 4; ++j) w2[j] = *(const uint4*)(p + 8*j);
  }
  // biases
  const float bq0 = bq[h*64 + d];
  const float bq1 = biasws[h*64 + d];
  const float bmd = bmel[h*64 + half*32 + ((tid & 255) >> 3)];   // gap mel bias
  float bgi0=0, bgg0=0, bgo0=0, bgi1=0, bgg1=0, bgo1=0;
  if (tid < 256){
    bgi0 = biasws[ 512 + tid]; bgg0 = biasws[1024 + tid]; bgo0 = biasws[1280 + tid];
    bgi1 = biasws[1536 + tid]; bgg1 = biasws[2048 + tid]; bgo1 = biasws[2304 + tid];
  }
  float4 wst4 = {0.f,0.f,0.f,0.f};
  if (h == 0 && half == 1 && tid < 64) wst4 = *(const float4*)(Wstop + tid*4);
  const float bst = bstop[0];

  if (tid < 256) l_h[tid] = 0.f;
  if (tid < 288) l_hw[tid] = 0.f;
  float hreg = 0.f;
  __syncthreads();

  int rot = 0;
  for (int t = 0; t < 1000; ++t){
    float* buf = Gbuf + (rot*16 + b)*768;
    // ---- P1: q partials (all) + W2m partials -> aadd (tid<384) + reset ----
    {
      const float4* hh = (const float4*)(l_h + ko*32);
      l_qt[ko][d] = dot8f(wq[0], wq[1], hh[0], hh[1]) + dot8f(wq[2], wq[3], hh[2], hh[3])
                  + dot8f(wq[4], wq[5], hh[4], hh[5]) + dot8f(wq[6], wq[7], hh[6], hh[7]);
    }
    if (tid < 384){
      const float4* hh = (const float4*)(l_hw + c8*36);
      float w2p = dot8(w2[0], hh[0], hh[1]) + dot8(w2[1], hh[2], hh[3])
                + dot8(w2[2], hh[4], hh[5]) + dot8(w2[3], hh[6], hh[7]);
      w2p += __shfl_xor(w2p, 1);
      w2p += __shfl_xor(w2p, 2);
      w2p += __shfl_xor(w2p, 4);               // combine 8 col-chunks
      if (c8 == 0) aadd(buf + r2, w2p);
    } else if (t >= 2 && tid >= 432 && tid < 480){
      // reset buffer of step t-2 (== buffer for t+1): all readers finished
      // before flag(t), which this block has passed (end of step t-1).
      int rr = rot + 1; if (rr == 3) rr = 0;
      afstore(Gbuf + (rr*16 + b)*768 + sidx*48 + (tid - 432), 0.f);
    }
    __syncthreads();
    // ---- wave0: q assemble, QK^T, softmax, ctx — no internal barriers ----
    if (tid < 64){
      float qq = (t == 0 ? bq0 : bq1);
      #pragma unroll
      for (int k = 0; k < 8; ++k) qq += l_qt[k][tid];
      l_q[tid] = qq;
      __asm__ __volatile__("s_waitcnt lgkmcnt(0)" ::: "memory");
      const float* kr0 = lK + tid*68;
      const float* kr1 = lK + (tid + 64)*68;
      float s0 = 0.f, s1 = 0.f;
      #pragma unroll
      for (int k = 0; k < 64; k += 8){
        float4 qa = *(const float4*)(l_q + k), qb = *(const float4*)(l_q + k + 4);
        s0 += dot8f(*(const float4*)(kr0 + k), *(const float4*)(kr0 + k + 4), qa, qb);
        s1 += dot8f(*(const float4*)(kr1 + k), *(const float4*)(kr1 + k + 4), qa, qb);
      }
      s0 *= 0.125f; s1 *= 0.125f;
      float m = fmaxf(s0, s1);
      #pragma unroll
      for (int off = 32; off; off >>= 1) m = fmaxf(m, __shfl_xor(m, off));
      float p0 = __expf(s0 - m), p1 = __expf(s1 - m);
      float ss = p0 + p1;
      #pragma unroll
      for (int off = 32; off; off >>= 1) ss += __shfl_xor(ss, off);
      l_p[tid] = p0; l_p[tid + 64] = p1;
      __asm__ __volatile__("s_waitcnt lgkmcnt(0)" ::: "memory");
      // ctx[d]: row-per-lane over lV (2-way free), l_p broadcast
      const float* vr = lV + tid*132;
      float cs = 0.f;
      #pragma unroll
      for (int k = 0; k < 128; k += 8)
        cs += dot8f(*(const float4*)(vr + k), *(const float4*)(vr + k + 4),
                    *(const float4*)(l_p + k), *(const float4*)(l_p + k + 4));
      l_ct[tid] = cs / ss;
      if (tid == 0) l_r[0] = ss;
    }
    __syncthreads();
    // ---- P5: Wcg gate partials (registers) -> per-batch aadd ----
    {
      const float4* ct = (const float4*)(l_ct + c4*16);
      float4 c0 = ct[0], c1 = ct[1], c2 = ct[2], c3 = ct[3];
      float pr0 = dot8(wcg[0][0], c0, c1) + dot8(wcg[0][1], c2, c3);
      float pr1 = dot8(wcg[1][0], c0, c1) + dot8(wcg[1][1], c2, c3);
      float pr2 = dot8(wcg[2][0], c0, c1) + dot8(wcg[2][1], c2, c3);
      pr0 += __shfl_xor(pr0, 1); pr0 += __shfl_xor(pr0, 2);
      pr1 += __shfl_xor(pr1, 1); pr1 += __shfl_xor(pr1, 2);
      pr2 += __shfl_xor(pr2, 1); pr2 += __shfl_xor(pr2, 2);
      if (c4 == 0){
        const int rb = half*384 + rg*3;
        aadd(buf + rb,     pr0);
        aadd(buf + rb + 1, pr1);
        aadd(buf + rb + 2, pr2);
      }
    }
    bar_arrive(bflag, sidx, t+1);                // drains adds, then flag
    // ---- gap (hidden under RT, sync-free): partner wait @t==1, mel/stop ----
    if (t == 1) bar_wait(bars + (b ^ 1)*512, 16, 1);  // partner preludes done
    if (t > 0){
      if (tid < 256){
        const int dd = half*32 + (tid >> 3), cc = tid & 7;
        const float* pm = Wmel + (h*64 + dd)*256 + cc*32;
        const float4* hh = (const float4*)(l_hw + cc*36);  // staggered, free
        float mp = dot8f(*(const float4*)(pm),      *(const float4*)(pm + 4),  hh[0], hh[1])
                 + dot8f(*(const float4*)(pm + 8),  *(const float4*)(pm + 12), hh[2], hh[3])
                 + dot8f(*(const float4*)(pm + 16), *(const float4*)(pm + 20), hh[4], hh[5])
                 + dot8f(*(const float4*)(pm + 24), *(const float4*)(pm + 28), hh[6], hh[7]);
        mp += __shfl_xor(mp, 1); mp += __shfl_xor(mp, 2); mp += __shfl_xor(mp, 4);
        if (cc == 0) out_mel[((size_t)b*1000 + (t-1))*512 + h*64 + dd] = mp + bmd;
      }
      if (h == 0 && half == 1 && tid < 64){
        const float4 h4v = *(const float4*)(l_h + tid*4);
        float sp = wst4.x*h4v.x + wst4.y*h4v.y + wst4.z*h4v.z + wst4.w*h4v.w;
        #pragma unroll
        for (int off = 32; off; off >>= 1) sp += __shfl_xor(sp, off);
        if (tid == 0) out_stop[b*1000 + (t-1)] = sp + bst;
      }
    }
    bar_wait(bflag, 16, t+1);                    // one RT per step
    // ---- P6: redundant h_t from summed gates (f-gates skipped) ----
    if (tid < 256){
      float gi = (t == 0 ? bgi0 : bgi1) + afload(buf + tid);
      float gg = (t == 0 ? bgg0 : bgg1) + afload(buf + 256 + tid);
      float go = (t == 0 ? bgo0 : bgo1) + afload(buf + 512 + tid);
      float c = sigm(gi) * tanhf(gg);            // decoder c_prev == 0 every step
      hreg = sigm(go) * tanhf(c);
      l_h[tid] = hreg;
      l_hw[(tid >> 5)*36 + (tid & 31)] = hreg;
    }
    __syncthreads();
    rot = (rot == 2) ? 0 : rot + 1;
  }

  // ---- epilogue: mel/stop for t=999; publish probs; head-avg attn ----
  if (tid < 256){
    const int dd = half*32 + (tid >> 3), cc = tid & 7;
    const float* pm = Wmel + (h*64 + dd)*256 + cc*32;
    const float4* hh = (const float4*)(l_hw + cc*36);
    float mp = dot8f(*(const float4*)(pm),      *(const float4*)(pm + 4),  hh[0], hh[1])
             + dot8f(*(const float4*)(pm + 8),  *(const float4*)(pm + 12), hh[2], hh[3])
             + dot8f(*(const float4*)(pm + 16), *(const float4*)(pm + 20), hh[4], hh[5])
             + dot8f(*(const float4*)(pm + 24), *(const float4*)(pm + 28), hh[6], hh[7]);
    mp += __shfl_xor(mp, 1); mp += __shfl_xor(mp, 2); mp += __shfl_xor(mp, 4);
    if (cc == 0) out_mel[((size_t)b*1000 + 999)*512 + h*64 + dd] = mp + bmd;
  }
  if (h == 0 && half == 1 && tid < 64){
    const float4 h4v = *(const float4*)(l_h + tid*4);
    float sp = wst4.x*h4v.x + wst4.y*h4v.y + wst4.z*h4v.z + wst4.w*h4v.w;
    #pragma unroll
    for (int off = 32; off; off >>= 1) sp += __shfl_xor(sp, off);
    if (tid == 0) out_stop[b*1000 + 999] = sp + bst;
  }
  if (half == 0 && tid < 128)   // l_p/l_r hold step-999 values; normalize here
    afstore(probs + (b*8 + h)*128 + tid, l_p[tid] / l_r[0]);
  bar_arrive(bflag, sidx, 1001);                 // probs drained before flag
  if (h == 0 && half == 0){
    bar_wait(bflag, 16, 1001);
    if (tid < 128){
      float ssum = 0.f;
      #pragma unroll
      for (int hh = 0; hh < 8; ++hh) ssum += afload(probs + (b*8 + hh)*128 + tid);
      out_attn[b*128 + tid] = ssum * 0.125f;
    }
  }
}

extern "C" void kernel_launch(void* const* d_in, const int* in_sizes, int n_in,
                              void* d_out, int out_size, void* d_ws, size_t ws_size,
                              hipStream_t stream){
  const int*   tok = (const int*)d_in[0];
  const int*   spk = (const int*)d_in[1];
  const float* emb_text = (const float*)d_in[2];
  const float* emb_spk  = (const float*)d_in[3];
  const float* WihF = (const float*)d_in[4];
  const float* WhhF = (const float*)d_in[5];
  const float* bihF = (const float*)d_in[6];
  const float* bhhF = (const float*)d_in[7];
  const float* WihB = (const float*)d_in[8];
  const float* WhhB = (const float*)d_in[9];
  const float* bihB = (const float*)d_in[10];
  const float* bhhB = (const float*)d_in[11];
  const float* Wq = (const float*)d_in[12];
  const float* bq = (const float*)d_in[13];
  const float* Wk = (const float*)d_in[14];
  const float* bk = (const float*)d_in[15];
  const float* Wv = (const float*)d_in[16];
  const float* bv = (const float*)d_in[17];
  const float* Wo = (const float*)d_in[18];
  const float* bo = (const float*)d_in[19];
  const float* decW = (const float*)d_in[20];
  /* d_in[21] dec_Whh dead (state re-zeroed every step) */
  const float* bih = (const float*)d_in[22];
  const float* bhh = (const float*)d_in[23];
  const float* Wmel = (const float*)d_in[24];
  const float* bmel = (const float*)d_in[25];
  const float* Wstop = (const float*)d_in[26];
  const float* bstop = (const float*)d_in[27];

  char* ws = (char*)d_ws;
  int*   bars   = (int*)(ws + WS_BAR);
  float* Gbuf   = (float*)(ws + WS_GBUF);
  float* hbuf   = (float*)(ws + WS_HBUF);
  float* probs  = (float*)(ws + WS_PROBS);
  float* biasws = (float*)(ws + WS_BIAS);
  u16*   W2m    = (u16*)(ws + WS_W2M);
  float* Wqh    = (float*)(ws + WS_WQH);
  u16*   Wcg    = (u16*)(ws + WS_WCG);

  float* outf = (float*)d_out;
  float* encA = outf + OF_ENC_A;
  float* encB = outf + OF_ENC_B;
  float* xwf  = outf + OF_XWF;
  float* xwb  = outf + OF_XWB;

  k_init <<<32,   256, 0, stream>>>(bars, hbuf);
  k_xw   <<<2048, 256, 0, stream>>>(tok, spk, emb_text, emb_spk,
                                    WihF, bihF, bhhF, WihB, bihB, bhhB, xwf, xwb);
  k_enc  <<<256,  128, 0, stream>>>(xwf, xwb, WhhF, WhhB, encA, encB, bars);
  k_fuse <<<896,  256, 0, stream>>>(decW, Wo, Wmel, Wq, Wcg, W2m, Wqh);
  k_bias <<<6,    256, 0, stream>>>(Wq, bq, bmel, decW, bo, bih, bhh, biasws);
  k_proj <<<1024, 256, 0, stream>>>(encA, encB, Wk, bk, Wv, bv, outf);
  k_decode<<<256, 512, 0, stream>>>(Wqh, Wcg, W2m, Wmel, bmel, Wstop, bstop,
                                    bq, biasws, Gbuf, probs, bars, outf);
}